// Round 3
// baseline (260.197 us; speedup 1.0000x reference)
//
#include <hip/hip_runtime.h>
#include <hip/hip_bf16.h>

#define N_NODES 50000
#define N_EDGES 800000
#define NB_SCAN 196  // ceil(50000/256)

typedef __bf16 bf16x8 __attribute__((ext_vector_type(8)));
typedef float  f32x4  __attribute__((ext_vector_type(4)));

__device__ __forceinline__ ushort f2bf(float f) {
    __hip_bfloat16 h = __float2bfloat16(f);
    return __builtin_bit_cast(ushort, h);
}
__device__ __forceinline__ float bf2f(ushort u) {
    return __builtin_bit_cast(float, (unsigned)u << 16);
}

// ---------------- CSR build ----------------

__global__ void k_hist(const int* __restrict__ ei, int* __restrict__ cnt) {
    int e = blockIdx.x * 256 + threadIdx.x;
    if (e < N_EDGES) atomicAdd(&cnt[ei[N_EDGES + e]], 1);
}

__global__ __launch_bounds__(256) void k_scan1(const int* __restrict__ cnt,
                                               int* __restrict__ tmp,
                                               int* __restrict__ bsum) {
    __shared__ int ws[256];
    int t = threadIdx.x, i = blockIdx.x * 256 + t;
    int v = (i < N_NODES) ? cnt[i] : 0;
    ws[t] = v;
    __syncthreads();
#pragma unroll
    for (int off = 1; off < 256; off <<= 1) {
        int u = (t >= off) ? ws[t - off] : 0;
        __syncthreads();
        ws[t] += u;
        __syncthreads();
    }
    if (i < N_NODES) tmp[i] = ws[t] - v;
    if (t == 255) bsum[blockIdx.x] = ws[255];
}

__global__ __launch_bounds__(256) void k_scan2(const int* __restrict__ bsum,
                                               int* __restrict__ boff,
                                               int* __restrict__ offs) {
    __shared__ int ws[256];
    int t = threadIdx.x;
    int v = (t < NB_SCAN) ? bsum[t] : 0;
    ws[t] = v;
    __syncthreads();
#pragma unroll
    for (int off = 1; off < 256; off <<= 1) {
        int u = (t >= off) ? ws[t - off] : 0;
        __syncthreads();
        ws[t] += u;
        __syncthreads();
    }
    if (t < NB_SCAN) boff[t] = ws[t] - v;
    if (t == 255) offs[N_NODES] = ws[255];
}

__global__ __launch_bounds__(256) void k_scan3(const int* __restrict__ tmp,
                                               const int* __restrict__ boff,
                                               int* __restrict__ offs,
                                               int* __restrict__ cursor) {
    int i = blockIdx.x * 256 + threadIdx.x;
    if (i < N_NODES) {
        int o = tmp[i] + boff[blockIdx.x];
        offs[i] = o;
        cursor[i] = o;
    }
}

__global__ void k_scatter(const int* __restrict__ ei, int* __restrict__ cursor,
                          int* __restrict__ elist) {
    int e = blockIdx.x * 256 + threadIdx.x;
    if (e < N_EDGES) {
        int d = ei[N_EDGES + e];
        int pos = atomicAdd(&cursor[d], 1);
        elist[pos] = ei[e];
    }
}

// ---------------- x -> bf16 cast (halves aggregation gather bytes) ----------------
__global__ void k_cast(const float* __restrict__ x, ushort* __restrict__ xb) {
    int i = blockIdx.x * 256 + threadIdx.x;  // 8 elems each
    const float4* x4 = (const float4*)x;
    float4 a = x4[i * 2], b = x4[i * 2 + 1];
    ushort o[8];
    o[0] = f2bf(a.x); o[1] = f2bf(a.y); o[2] = f2bf(a.z); o[3] = f2bf(a.w);
    o[4] = f2bf(b.x); o[5] = f2bf(b.y); o[6] = f2bf(b.z); o[7] = f2bf(b.w);
    *(uint4*)(xb + (size_t)i * 8) = *(uint4*)o;
}

// ---------------- weight prep: transpose + bf16 cast ----------------
__device__ __forceinline__ void transpose_one(const float* W, ushort* WT,
                                              int K, int N, int t) {
    int k = t / N, n = t % N;
    WT[n * K + k] = f2bf(W[t]);
}

__global__ void k_transpose_all(const float* __restrict__ W1, ushort* __restrict__ W1T,
                                const float* __restrict__ W2, ushort* __restrict__ W2T,
                                const float* __restrict__ Wc, ushort* __restrict__ WcT) {
    int t = blockIdx.x * 256 + threadIdx.x;
    const int S1 = 128 * 256, S2 = 256 * 256, S3 = 256 * 64;
    if (t < S1) transpose_one(W1, W1T, 128, 256, t);
    else if (t < S1 + S2) transpose_one(W2, W2T, 256, 256, t - S1);
    else if (t < S1 + S2 + S3) transpose_one(Wc, WcT, 256, 64, t - S1 - S2);
}

// ---------------- aggregation (bf16 gather): hsum[i] = x[i] + sum_{j->i} x[j] ----------------
// 32-lane group per node; row = 128 bf16 = 32 lanes x ushort4 (8B)
__global__ __launch_bounds__(256) void k_aggregate(const ushort* __restrict__ xb,
                                                   const int* __restrict__ offs,
                                                   const int* __restrict__ elist,
                                                   ushort* __restrict__ hsum) {
    int g = threadIdx.x >> 5, lane = threadIdx.x & 31;
    int node = blockIdx.x * 8 + g;
    if (node >= N_NODES) return;
    const ushort4* x4 = (const ushort4*)xb;
    ushort4 mine = x4[(size_t)node * 32 + lane];
    float acc0 = bf2f(mine.x), acc1 = bf2f(mine.y), acc2 = bf2f(mine.z), acc3 = bf2f(mine.w);
    int beg = offs[node], end = offs[node + 1];
    for (int base = beg; base < end; base += 32) {
        int m = end - base;
        int idx = 0;
        if (lane < m) idx = elist[base + lane];
        int c = m < 32 ? m : 32;
        for (int j = 0; j < c; ++j) {
            int s = __shfl(idx, j, 32);
            ushort4 v = x4[(size_t)s * 32 + lane];
            acc0 += bf2f(v.x); acc1 += bf2f(v.y); acc2 += bf2f(v.z); acc3 += bf2f(v.w);
        }
    }
    ushort4 o;
    o.x = f2bf(acc0); o.y = f2bf(acc1); o.z = f2bf(acc2); o.w = f2bf(acc3);
    *(ushort4*)(hsum + (size_t)node * 128 + lane * 4) = o;
}

// ---------------- fused 3-stage MLP ----------------
// block = 256 threads (4 waves), 64 rows. Chain through LDS ping-pong:
//   buf0: hsum[64x128] -> (stage1) -> buf1: relu(h1)[64x256]
//   -> (stage2) -> buf0: relu(h2)[64x256] -> (stage3) -> out f32 [64x64]
// B-fragments read directly from global (weights are 448KB total, L2-hot).
__global__ __launch_bounds__(256) void k_mlp(const ushort* __restrict__ hsum,
                                             const ushort* __restrict__ W1T,
                                             const float* __restrict__ b1,
                                             const ushort* __restrict__ W2T,
                                             const float* __restrict__ b2,
                                             const ushort* __restrict__ WcT,
                                             const float* __restrict__ bc,
                                             float* __restrict__ out, int M) {
    constexpr int LP = 264;  // 528B row stride -> rows differ by 4 banks -> 2-way (free)
    __shared__ ushort buf0[64 * LP];
    __shared__ ushort buf1[64 * LP];
    int m0 = blockIdx.x * 64;
    int tid = threadIdx.x, wid = tid >> 6, lane = tid & 63;
    int lr = lane & 15;          // A-row-in-tile / B+C col-in-tile
    int kq = (lane >> 4) << 3;   // k-subgroup byte-pair offset (in bf16 elems)
    int arow = (wid << 4) + lr;
    int r0l = (wid << 4) + ((lane >> 4) << 2);  // local C row base

    // stage hsum tile [64 x 128] bf16
    for (int c = tid; c < 64 * 16; c += 256) {
        int r = c >> 4, k8 = c & 15;
        uint4 v = make_uint4(0, 0, 0, 0);
        int gr = m0 + r;
        if (gr < M) v = *(const uint4*)(hsum + (size_t)gr * 128 + k8 * 8);
        *(uint4*)(buf0 + r * LP + k8 * 8) = v;
    }
    __syncthreads();

    // ---- stage 1: relu(hsum @ W1 + b1)  (K=128, N=256 -> 16 col-tiles)
    f32x4 acc[16];
#pragma unroll
    for (int n = 0; n < 16; ++n) acc[n] = 0;
#pragma unroll
    for (int kk = 0; kk < 128; kk += 32) {
        bf16x8 a = __builtin_bit_cast(bf16x8, *(const uint4*)(buf0 + arow * LP + kk + kq));
#pragma unroll
        for (int n = 0; n < 16; ++n) {
            bf16x8 b = __builtin_bit_cast(bf16x8,
                *(const uint4*)(W1T + (size_t)((n << 4) + lr) * 128 + kk + kq));
            acc[n] = __builtin_amdgcn_mfma_f32_16x16x32_bf16(a, b, acc[n], 0, 0, 0);
        }
    }
#pragma unroll
    for (int n = 0; n < 16; ++n) {
        int col = (n << 4) + lr;
        float bv = b1[col];
#pragma unroll
        for (int r = 0; r < 4; ++r)
            buf1[(r0l + r) * LP + col] = f2bf(fmaxf(acc[n][r] + bv, 0.0f));
    }
    __syncthreads();

    // ---- stage 2: relu(h1 @ W2 + b2)  (K=256, N=256)
#pragma unroll
    for (int n = 0; n < 16; ++n) acc[n] = 0;
#pragma unroll
    for (int kk = 0; kk < 256; kk += 32) {
        bf16x8 a = __builtin_bit_cast(bf16x8, *(const uint4*)(buf1 + arow * LP + kk + kq));
#pragma unroll
        for (int n = 0; n < 16; ++n) {
            bf16x8 b = __builtin_bit_cast(bf16x8,
                *(const uint4*)(W2T + (size_t)((n << 4) + lr) * 256 + kk + kq));
            acc[n] = __builtin_amdgcn_mfma_f32_16x16x32_bf16(a, b, acc[n], 0, 0, 0);
        }
    }
    __syncthreads();  // everyone done with buf0 before overwrite
#pragma unroll
    for (int n = 0; n < 16; ++n) {
        int col = (n << 4) + lr;
        float bv = b2[col];
#pragma unroll
        for (int r = 0; r < 4; ++r)
            buf0[(r0l + r) * LP + col] = f2bf(fmaxf(acc[n][r] + bv, 0.0f));
    }
    __syncthreads();

    // ---- stage 3: relu(h2) @ Wc + bc  (K=256, N=64 -> 4 col-tiles), f32 out
    f32x4 acc3[4];
#pragma unroll
    for (int n = 0; n < 4; ++n) acc3[n] = 0;
#pragma unroll
    for (int kk = 0; kk < 256; kk += 32) {
        bf16x8 a = __builtin_bit_cast(bf16x8, *(const uint4*)(buf0 + arow * LP + kk + kq));
#pragma unroll
        for (int n = 0; n < 4; ++n) {
            bf16x8 b = __builtin_bit_cast(bf16x8,
                *(const uint4*)(WcT + (size_t)((n << 4) + lr) * 256 + kk + kq));
            acc3[n] = __builtin_amdgcn_mfma_f32_16x16x32_bf16(a, b, acc3[n], 0, 0, 0);
        }
    }
    int r0g = m0 + r0l;
#pragma unroll
    for (int n = 0; n < 4; ++n) {
        int col = (n << 4) + lr;
        float bv = bc[col];
#pragma unroll
        for (int r = 0; r < 4; ++r) {
            int grow = r0g + r;
            if (grow < M) out[(size_t)grow * 64 + col] = acc3[n][r] + bv;
        }
    }
}

// ---------------- launch ----------------

extern "C" void kernel_launch(void* const* d_in, const int* in_sizes, int n_in,
                              void* d_out, int out_size, void* d_ws, size_t ws_size,
                              hipStream_t stream) {
    const float* x  = (const float*)d_in[0];
    const int*   ei = (const int*)d_in[1];   // [2, 800000]: row0 = src, row1 = dst
    const float* W1 = (const float*)d_in[2];
    const float* b1 = (const float*)d_in[3];
    const float* W2 = (const float*)d_in[4];
    const float* b2 = (const float*)d_in[5];
    const float* Wc = (const float*)d_in[6];
    const float* bc = (const float*)d_in[7];
    float* out = (float*)d_out;

    // workspace carve (all segments 16B-aligned)
    char* p = (char*)d_ws;
    int* offs   = (int*)p; p += (N_NODES + 4) * 4;
    int* cursor = (int*)p; p += N_NODES * 4;
    int* cnt    = (int*)p; p += N_NODES * 4;
    int* tmp    = (int*)p; p += N_NODES * 4;
    int* bsum   = (int*)p; p += 256 * 4;
    int* boff   = (int*)p; p += 256 * 4;
    int* elist  = (int*)p; p += N_EDGES * 4;
    ushort* W1T = (ushort*)p; p += 256 * 128 * 2;
    ushort* W2T = (ushort*)p; p += 256 * 256 * 2;
    ushort* WcT = (ushort*)p; p += 64 * 256 * 2;
    ushort* xb  = (ushort*)p; p += (size_t)N_NODES * 128 * 2;
    ushort* hsum = (ushort*)p; p += (size_t)N_NODES * 128 * 2;

    hipMemsetAsync(cnt, 0, N_NODES * 4, stream);
    k_hist<<<N_EDGES / 256, 256, 0, stream>>>(ei, cnt);
    k_scan1<<<NB_SCAN, 256, 0, stream>>>(cnt, tmp, bsum);
    k_scan2<<<1, 256, 0, stream>>>(bsum, boff, offs);
    k_scan3<<<NB_SCAN, 256, 0, stream>>>(tmp, boff, offs, cursor);
    k_scatter<<<N_EDGES / 256, 256, 0, stream>>>(ei, cursor, elist);

    k_cast<<<(N_NODES * 128 / 8) / 256, 256, 0, stream>>>(x, xb);
    k_transpose_all<<<(128 * 256 + 256 * 256 + 256 * 64 + 255) / 256, 256, 0, stream>>>(
        W1, W1T, W2, W2T, Wc, WcT);

    k_aggregate<<<N_NODES / 8, 256, 0, stream>>>(xb, offs, elist, hsum);

    k_mlp<<<(N_NODES + 63) / 64, 256, 0, stream>>>(hsum, W1T, b1, W2T, b2, WcT, bc,
                                                   out, N_NODES);
}

// Round 4
// 231.214 us; speedup vs baseline: 1.1254x; 1.1254x over previous
//
#include <hip/hip_runtime.h>
#include <hip/hip_bf16.h>

#define N_NODES 50000
#define M_PAD   50048   // 391 * 128, so GEMM staging never reads past allocations
#define N_EDGES 800000
#define NB_SCAN 196     // ceil(50000/256)

typedef __bf16 bf16x8 __attribute__((ext_vector_type(8)));
typedef float  f32x4  __attribute__((ext_vector_type(4)));

__device__ __forceinline__ ushort f2bf(float f) {
    __hip_bfloat16 h = __float2bfloat16(f);
    return __builtin_bit_cast(ushort, h);
}
__device__ __forceinline__ float bf2f(ushort u) {
    return __builtin_bit_cast(float, (unsigned)u << 16);
}

// async global->LDS, 16B per lane; lds base must be wave-uniform
__device__ __forceinline__ void gload16(const ushort* g, ushort* l) {
    __builtin_amdgcn_global_load_lds(
        (const __attribute__((address_space(1))) unsigned*)g,
        (__attribute__((address_space(3))) unsigned*)l, 16, 0, 0);
}

// ---------------- CSR build ----------------

__global__ void k_hist(const int* __restrict__ ei, int* __restrict__ cnt) {
    int e = blockIdx.x * 256 + threadIdx.x;
    if (e < N_EDGES) atomicAdd(&cnt[ei[N_EDGES + e]], 1);
}

__global__ __launch_bounds__(256) void k_scan1(const int* __restrict__ cnt,
                                               int* __restrict__ tmp,
                                               int* __restrict__ bsum) {
    __shared__ int ws[256];
    int t = threadIdx.x, i = blockIdx.x * 256 + t;
    int v = (i < N_NODES) ? cnt[i] : 0;
    ws[t] = v;
    __syncthreads();
#pragma unroll
    for (int off = 1; off < 256; off <<= 1) {
        int u = (t >= off) ? ws[t - off] : 0;
        __syncthreads();
        ws[t] += u;
        __syncthreads();
    }
    if (i < N_NODES) tmp[i] = ws[t] - v;
    if (t == 255) bsum[blockIdx.x] = ws[255];
}

__global__ __launch_bounds__(256) void k_scan2(const int* __restrict__ bsum,
                                               int* __restrict__ boff,
                                               int* __restrict__ offs) {
    __shared__ int ws[256];
    int t = threadIdx.x;
    int v = (t < NB_SCAN) ? bsum[t] : 0;
    ws[t] = v;
    __syncthreads();
#pragma unroll
    for (int off = 1; off < 256; off <<= 1) {
        int u = (t >= off) ? ws[t - off] : 0;
        __syncthreads();
        ws[t] += u;
        __syncthreads();
    }
    if (t < NB_SCAN) boff[t] = ws[t] - v;
    if (t == 255) offs[N_NODES] = ws[255];
}

__global__ __launch_bounds__(256) void k_scan3(const int* __restrict__ tmp,
                                               const int* __restrict__ boff,
                                               int* __restrict__ offs,
                                               int* __restrict__ cursor) {
    int i = blockIdx.x * 256 + threadIdx.x;
    if (i < N_NODES) {
        int o = tmp[i] + boff[blockIdx.x];
        offs[i] = o;
        cursor[i] = o;
    }
}

__global__ void k_scatter(const int* __restrict__ ei, int* __restrict__ cursor,
                          int* __restrict__ elist) {
    int e = blockIdx.x * 256 + threadIdx.x;
    if (e < N_EDGES) {
        int d = ei[N_EDGES + e];
        int pos = atomicAdd(&cursor[d], 1);
        elist[pos] = ei[e];
    }
}

// ---------------- x -> bf16 cast ----------------
__global__ void k_cast(const float* __restrict__ x, ushort* __restrict__ xb) {
    int i = blockIdx.x * 256 + threadIdx.x;  // 8 elems each
    const float4* x4 = (const float4*)x;
    float4 a = x4[i * 2], b = x4[i * 2 + 1];
    ushort o[8];
    o[0] = f2bf(a.x); o[1] = f2bf(a.y); o[2] = f2bf(a.z); o[3] = f2bf(a.w);
    o[4] = f2bf(b.x); o[5] = f2bf(b.y); o[6] = f2bf(b.z); o[7] = f2bf(b.w);
    *(uint4*)(xb + (size_t)i * 8) = *(uint4*)o;
}

// ---------------- weight prep: transpose + bf16 cast ----------------
__device__ __forceinline__ void transpose_one(const float* W, ushort* WT,
                                              int K, int N, int t) {
    int k = t / N, n = t % N;
    WT[n * K + k] = f2bf(W[t]);
}

__global__ void k_transpose_all(const float* __restrict__ W1, ushort* __restrict__ W1T,
                                const float* __restrict__ W2, ushort* __restrict__ W2T,
                                const float* __restrict__ Wc, ushort* __restrict__ WcT) {
    int t = blockIdx.x * 256 + threadIdx.x;
    const int S1 = 128 * 256, S2 = 256 * 256, S3 = 256 * 64;
    if (t < S1) transpose_one(W1, W1T, 128, 256, t);
    else if (t < S1 + S2) transpose_one(W2, W2T, 256, 256, t - S1);
    else if (t < S1 + S2 + S3) transpose_one(Wc, WcT, 256, 64, t - S1 - S2);
}

// ---------------- aggregation (bf16 gather): hsum[i] = x[i] + sum_{j->i} x[j] ----------------
__global__ __launch_bounds__(256) void k_aggregate(const ushort* __restrict__ xb,
                                                   const int* __restrict__ offs,
                                                   const int* __restrict__ elist,
                                                   ushort* __restrict__ hsum) {
    int g = threadIdx.x >> 5, lane = threadIdx.x & 31;
    int node = blockIdx.x * 8 + g;
    if (node >= N_NODES) return;
    const ushort4* x4 = (const ushort4*)xb;
    ushort4 mine = x4[(size_t)node * 32 + lane];
    float acc0 = bf2f(mine.x), acc1 = bf2f(mine.y), acc2 = bf2f(mine.z), acc3 = bf2f(mine.w);
    int beg = offs[node], end = offs[node + 1];
    for (int base = beg; base < end; base += 32) {
        int m = end - base;
        int idx = 0;
        if (lane < m) idx = elist[base + lane];
        int c = m < 32 ? m : 32;
        for (int j = 0; j < c; ++j) {
            int s = __shfl(idx, j, 32);
            ushort4 v = x4[(size_t)s * 32 + lane];
            acc0 += bf2f(v.x); acc1 += bf2f(v.y); acc2 += bf2f(v.z); acc3 += bf2f(v.w);
        }
    }
    ushort4 o;
    o.x = f2bf(acc0); o.y = f2bf(acc1); o.z = f2bf(acc2); o.w = f2bf(acc3);
    *(ushort4*)(hsum + (size_t)node * 128 + lane * 4) = o;
}

// ---------------- m97-style bf16 MFMA GEMM ----------------
// BM=128, BK=64, 256 threads (4 waves). async global_load_lds staging with
// both-sides XOR chunk swizzle (linear LDS dest, pre-swizzled global source,
// same XOR on the ds_read side): LDS[r][c16] = G[r][c16 ^ (r&7)].
// A: [M_PAD x K] bf16 row-major.  BT: [Nfull x K] bf16 row-major (weights^T).
template <int K, int BN, bool RELU, bool OUTF32>
__global__ __launch_bounds__(256) void k_gemm2(const ushort* __restrict__ A,
                                               const ushort* __restrict__ BT,
                                               const float* __restrict__ bias,
                                               void* __restrict__ Cout,
                                               int M, int Nfull) {
    constexpr int BM = 128, BK = 64;
    constexpr int WAVES_N = (BN == 128) ? 2 : 1;
    constexpr int WMROWS = BM / (4 / WAVES_N);   // 64 (BN=128) or 32 (BN=64)
    constexpr int WM = WMROWS / 16;              // 4 or 2
    constexpr int WN = (BN / WAVES_N) / 16;      // 4
    __shared__ ushort sA[BM * BK];
    __shared__ ushort sB[BN * BK];

    int m0 = blockIdx.x * BM, n0 = blockIdx.y * BN;
    int tid = threadIdx.x, wid = tid >> 6, lane = tid & 63;
    int lr = lane & 15;
    int kq = (lane >> 4) << 3;               // k-offset (elems) within 32-K step
    int l8 = lane >> 3, c8 = lane & 7;
    int swz = c8 ^ l8;                       // source 16B-chunk permutation

    int wrow0 = (wid / WAVES_N) * WMROWS;
    int wcol0 = (wid % WAVES_N) * 64;

    f32x4 acc[WM][WN];
#pragma unroll
    for (int m = 0; m < WM; ++m)
#pragma unroll
        for (int n = 0; n < WN; ++n) acc[m][n] = 0;

    for (int kb = 0; kb < K; kb += BK) {
        if (kb) __syncthreads();
        // stage A rows [wid*32, wid*32+32), 8 rows per issue
#pragma unroll
        for (int i = 0; i < 4; ++i) {
            int r = wid * 32 + i * 8;
            gload16(A + (size_t)(m0 + r + l8) * K + kb + swz * 8, sA + r * BK);
        }
        // stage B rows (BN/32 issues per wave)
#pragma unroll
        for (int i = 0; i < BN / 32; ++i) {
            int r = wid * (BN / 4) + i * 8;
            gload16(BT + (size_t)(n0 + r + l8) * K + kb + swz * 8, sB + r * BK);
        }
        __syncthreads();

#pragma unroll
        for (int kk = 0; kk < BK; kk += 32) {
            int cb = (kk + kq) * 2;  // byte col within 128B row
            bf16x8 af[WM], bfr[WN];
#pragma unroll
            for (int m = 0; m < WM; ++m) {
                int r = wrow0 + m * 16 + lr;
                af[m] = __builtin_bit_cast(bf16x8,
                    *(const uint4*)((const char*)sA + r * 128 + (cb ^ ((r & 7) << 4))));
            }
#pragma unroll
            for (int n = 0; n < WN; ++n) {
                int r = wcol0 + n * 16 + lr;
                bfr[n] = __builtin_bit_cast(bf16x8,
                    *(const uint4*)((const char*)sB + r * 128 + (cb ^ ((r & 7) << 4))));
            }
#pragma unroll
            for (int m = 0; m < WM; ++m)
#pragma unroll
                for (int n = 0; n < WN; ++n)
                    acc[m][n] = __builtin_amdgcn_mfma_f32_16x16x32_bf16(
                        af[m], bfr[n], acc[m][n], 0, 0, 0);
        }
    }

    // epilogue: C[row = base + (lane>>4)*4 + r][col = base + (lane&15)]
    int rbase = m0 + wrow0 + ((lane >> 4) << 2);
#pragma unroll
    for (int n = 0; n < WN; ++n) {
        int col = n0 + wcol0 + n * 16 + lr;
        float bv = bias[col];
#pragma unroll
        for (int m = 0; m < WM; ++m) {
#pragma unroll
            for (int r = 0; r < 4; ++r) {
                int grow = rbase + m * 16 + r;
                if (grow < M) {
                    float v = acc[m][n][r] + bv;
                    if (RELU) v = fmaxf(v, 0.0f);
                    if (OUTF32) ((float*)Cout)[(size_t)grow * Nfull + col] = v;
                    else        ((ushort*)Cout)[(size_t)grow * Nfull + col] = f2bf(v);
                }
            }
        }
    }
}

// ---------------- launch ----------------

extern "C" void kernel_launch(void* const* d_in, const int* in_sizes, int n_in,
                              void* d_out, int out_size, void* d_ws, size_t ws_size,
                              hipStream_t stream) {
    const float* x  = (const float*)d_in[0];
    const int*   ei = (const int*)d_in[1];   // [2, 800000]: row0 = src, row1 = dst
    const float* W1 = (const float*)d_in[2];
    const float* b1 = (const float*)d_in[3];
    const float* W2 = (const float*)d_in[4];
    const float* b2 = (const float*)d_in[5];
    const float* Wc = (const float*)d_in[6];
    const float* bc = (const float*)d_in[7];
    float* out = (float*)d_out;

    // workspace carve (all segments 16B-aligned)
    char* p = (char*)d_ws;
    int* offs   = (int*)p; p += (N_NODES + 4) * 4;
    int* cursor = (int*)p; p += N_NODES * 4;
    int* cnt    = (int*)p; p += N_NODES * 4;
    int* tmp    = (int*)p; p += N_NODES * 4;
    int* bsum   = (int*)p; p += 256 * 4;
    int* boff   = (int*)p; p += 256 * 4;
    int* elist  = (int*)p; p += N_EDGES * 4;
    ushort* W1T = (ushort*)p; p += 256 * 128 * 2;
    ushort* W2T = (ushort*)p; p += 256 * 256 * 2;
    ushort* WcT = (ushort*)p; p += 64 * 256 * 2;
    ushort* xb  = (ushort*)p; p += (size_t)N_NODES * 128 * 2;
    ushort* hsum = (ushort*)p; p += (size_t)M_PAD * 128 * 2;  // padded rows for staging
    ushort* h1  = (ushort*)p; p += (size_t)M_PAD * 256 * 2;
    ushort* h2  = (ushort*)p; p += (size_t)M_PAD * 256 * 2;

    hipMemsetAsync(cnt, 0, N_NODES * 4, stream);
    k_hist<<<N_EDGES / 256, 256, 0, stream>>>(ei, cnt);
    k_scan1<<<NB_SCAN, 256, 0, stream>>>(cnt, tmp, bsum);
    k_scan2<<<1, 256, 0, stream>>>(bsum, boff, offs);
    k_scan3<<<NB_SCAN, 256, 0, stream>>>(tmp, boff, offs, cursor);
    k_scatter<<<N_EDGES / 256, 256, 0, stream>>>(ei, cursor, elist);

    k_cast<<<(N_NODES * 128 / 8) / 256, 256, 0, stream>>>(x, xb);
    k_transpose_all<<<(128 * 256 + 256 * 256 + 256 * 64 + 255) / 256, 256, 0, stream>>>(
        W1, W1T, W2, W2T, Wc, WcT);

    k_aggregate<<<N_NODES / 8, 256, 0, stream>>>(xb, offs, elist, hsum);

    const int MT = M_PAD / 128;  // 391
    dim3 g1(MT, 2), g2(MT, 2), g3(MT, 1);
    k_gemm2<128, 128, true,  false><<<g1, 256, 0, stream>>>(hsum, W1T, b1, h1, N_NODES, 256);
    k_gemm2<256, 128, true,  false><<<g2, 256, 0, stream>>>(h1,   W2T, b2, h2, N_NODES, 256);
    k_gemm2<256, 64,  false, true ><<<g3, 256, 0, stream>>>(h2,   WcT, bc, out, N_NODES, 64);
}

// Round 5
// 215.326 us; speedup vs baseline: 1.2084x; 1.0738x over previous
//
#include <hip/hip_runtime.h>
#include <hip/hip_bf16.h>

#define N_NODES 50000
#define M_PAD   50048   // 391 * 128, so GEMM staging never reads past allocations
#define N_EDGES 800000
#define NB_SCAN 196     // ceil(50000/256)
#define NB_EDGE8 391    // ceil(800000/2048)
#define NB_CAST 3125    // 50000*128/8/256
#define NB_TR   448     // (128*256+256*256+256*64)/256

typedef __bf16 bf16x8 __attribute__((ext_vector_type(8)));
typedef float  f32x4  __attribute__((ext_vector_type(4)));

__device__ __forceinline__ ushort f2bf(float f) {
    __hip_bfloat16 h = __float2bfloat16(f);
    return __builtin_bit_cast(ushort, h);
}
__device__ __forceinline__ float bf2f(ushort u) {
    return __builtin_bit_cast(float, (unsigned)u << 16);
}

// async global->LDS, 16B per lane; lds base must be wave-uniform
__device__ __forceinline__ void gload16(const ushort* g, ushort* l) {
    __builtin_amdgcn_global_load_lds(
        (const __attribute__((address_space(1))) unsigned*)g,
        (__attribute__((address_space(3))) unsigned*)l, 16, 0, 0);
}

// ---------------- fused prep: edge histogram (ILP-8) + x cast + weight transpose ----------------
__device__ __forceinline__ void transpose_one(const float* W, ushort* WT,
                                              int K, int N, int t) {
    int k = t / N, n = t % N;
    WT[n * K + k] = f2bf(W[t]);
}

__global__ __launch_bounds__(256) void k_prep(const int* __restrict__ ei,
                                              int* __restrict__ cnt,
                                              const float* __restrict__ x,
                                              ushort* __restrict__ xb,
                                              const float* __restrict__ W1, ushort* __restrict__ W1T,
                                              const float* __restrict__ W2, ushort* __restrict__ W2T,
                                              const float* __restrict__ Wc, ushort* __restrict__ WcT) {
    int b = blockIdx.x, t = threadIdx.x;
    if (b < NB_EDGE8) {
        int base = b * 2048 + t;
        int d[8];
#pragma unroll
        for (int k = 0; k < 8; ++k) {
            int e = base + k * 256;
            d[k] = (e < N_EDGES) ? ei[N_EDGES + e] : -1;
        }
#pragma unroll
        for (int k = 0; k < 8; ++k)
            if (d[k] >= 0) atomicAdd(&cnt[d[k]], 1);
    } else if (b < NB_EDGE8 + NB_CAST) {
        int i = (b - NB_EDGE8) * 256 + t;  // 8 elems each
        const float4* x4 = (const float4*)x;
        float4 a = x4[(size_t)i * 2], bb = x4[(size_t)i * 2 + 1];
        ushort o[8];
        o[0] = f2bf(a.x); o[1] = f2bf(a.y); o[2] = f2bf(a.z); o[3] = f2bf(a.w);
        o[4] = f2bf(bb.x); o[5] = f2bf(bb.y); o[6] = f2bf(bb.z); o[7] = f2bf(bb.w);
        *(uint4*)(xb + (size_t)i * 8) = *(uint4*)o;
    } else {
        int tg = (b - NB_EDGE8 - NB_CAST) * 256 + t;
        const int S1 = 128 * 256, S2 = 256 * 256, S3 = 256 * 64;
        if (tg < S1) transpose_one(W1, W1T, 128, 256, tg);
        else if (tg < S1 + S2) transpose_one(W2, W2T, 256, 256, tg - S1);
        else if (tg < S1 + S2 + S3) transpose_one(Wc, WcT, 256, 64, tg - S1 - S2);
    }
}

// ---------------- scan phase 1: per-block scan of counts ----------------
__global__ __launch_bounds__(256) void k_scan1(const int* __restrict__ cnt,
                                               int* __restrict__ tmp,
                                               int* __restrict__ bsum) {
    __shared__ int ws[256];
    int t = threadIdx.x, i = blockIdx.x * 256 + t;
    int v = (i < N_NODES) ? cnt[i] : 0;
    ws[t] = v;
    __syncthreads();
#pragma unroll
    for (int off = 1; off < 256; off <<= 1) {
        int u = (t >= off) ? ws[t - off] : 0;
        __syncthreads();
        ws[t] += u;
        __syncthreads();
    }
    if (i < N_NODES) tmp[i] = ws[t] - v;
    if (t == 255) bsum[blockIdx.x] = ws[255];
}

// ---------------- scan phases 2+3 merged: every block redundantly scans bsum ----------------
__global__ __launch_bounds__(256) void k_scan23(const int* __restrict__ bsum,
                                                const int* __restrict__ tmp,
                                                int* __restrict__ offs,
                                                int* __restrict__ cursor) {
    __shared__ int ws[256], orig[256];
    int t = threadIdx.x;
    int v = (t < NB_SCAN) ? bsum[t] : 0;
    ws[t] = v; orig[t] = v;
    __syncthreads();
#pragma unroll
    for (int off = 1; off < 256; off <<= 1) {
        int u = (t >= off) ? ws[t - off] : 0;
        __syncthreads();
        ws[t] += u;
        __syncthreads();
    }
    int boff = ws[blockIdx.x] - orig[blockIdx.x];  // exclusive prefix for this block
    int i = blockIdx.x * 256 + t;
    if (i < N_NODES) {
        int o = tmp[i] + boff;
        offs[i] = o;
        cursor[i] = o;
    }
    if (blockIdx.x == 0 && t == 0) offs[N_NODES] = ws[NB_SCAN - 1];
}

// ---------------- scatter with ILP-8: 8 independent atomic+store chains per thread ----------------
__global__ __launch_bounds__(256) void k_scatter(const int* __restrict__ ei,
                                                 int* __restrict__ cursor,
                                                 int* __restrict__ elist) {
    int base = blockIdx.x * 2048 + threadIdx.x;
    int s[8], d[8], pos[8];
#pragma unroll
    for (int k = 0; k < 8; ++k) {
        int e = base + k * 256;
        bool ok = e < N_EDGES;
        int ee = ok ? e : 0;
        s[k] = ei[ee];
        d[k] = ok ? ei[N_EDGES + ee] : -1;
    }
#pragma unroll
    for (int k = 0; k < 8; ++k)
        if (d[k] >= 0) pos[k] = atomicAdd(&cursor[d[k]], 1);
#pragma unroll
    for (int k = 0; k < 8; ++k)
        if (d[k] >= 0) elist[pos[k]] = s[k];
}

// ---------------- aggregation (bf16 gather): hsum[i] = x[i] + sum_{j->i} x[j] ----------------
__global__ __launch_bounds__(256) void k_aggregate(const ushort* __restrict__ xb,
                                                   const int* __restrict__ offs,
                                                   const int* __restrict__ elist,
                                                   ushort* __restrict__ hsum) {
    int g = threadIdx.x >> 5, lane = threadIdx.x & 31;
    int node = blockIdx.x * 8 + g;
    if (node >= N_NODES) return;
    const ushort4* x4 = (const ushort4*)xb;
    ushort4 mine = x4[(size_t)node * 32 + lane];
    float acc0 = bf2f(mine.x), acc1 = bf2f(mine.y), acc2 = bf2f(mine.z), acc3 = bf2f(mine.w);
    int beg = offs[node], end = offs[node + 1];
    for (int base = beg; base < end; base += 32) {
        int m = end - base;
        int idx = 0;
        if (lane < m) idx = elist[base + lane];
        int c = m < 32 ? m : 32;
        for (int j = 0; j < c; ++j) {
            int s = __shfl(idx, j, 32);
            ushort4 v = x4[(size_t)s * 32 + lane];
            acc0 += bf2f(v.x); acc1 += bf2f(v.y); acc2 += bf2f(v.z); acc3 += bf2f(v.w);
        }
    }
    ushort4 o;
    o.x = f2bf(acc0); o.y = f2bf(acc1); o.z = f2bf(acc2); o.w = f2bf(acc3);
    *(ushort4*)(hsum + (size_t)node * 128 + lane * 4) = o;
}

// ---------------- m97-style bf16 MFMA GEMM ----------------
// BM=128, BK=64, 256 threads (4 waves). async global_load_lds staging with
// both-sides XOR chunk swizzle (linear LDS dest, pre-swizzled global source,
// same XOR on the ds_read side): LDS[r][c16] = G[r][c16 ^ (r&7)].
template <int K, int BN, bool RELU, bool OUTF32>
__global__ __launch_bounds__(256) void k_gemm2(const ushort* __restrict__ A,
                                               const ushort* __restrict__ BT,
                                               const float* __restrict__ bias,
                                               void* __restrict__ Cout,
                                               int M, int Nfull) {
    constexpr int BM = 128, BK = 64;
    constexpr int WAVES_N = (BN == 128) ? 2 : 1;
    constexpr int WMROWS = BM / (4 / WAVES_N);
    constexpr int WM = WMROWS / 16;
    constexpr int WN = (BN / WAVES_N) / 16;
    __shared__ ushort sA[BM * BK];
    __shared__ ushort sB[BN * BK];

    int m0 = blockIdx.x * BM, n0 = blockIdx.y * BN;
    int tid = threadIdx.x, wid = tid >> 6, lane = tid & 63;
    int lr = lane & 15;
    int kq = (lane >> 4) << 3;
    int l8 = lane >> 3, c8 = lane & 7;
    int swz = c8 ^ l8;

    int wrow0 = (wid / WAVES_N) * WMROWS;
    int wcol0 = (wid % WAVES_N) * 64;

    f32x4 acc[WM][WN];
#pragma unroll
    for (int m = 0; m < WM; ++m)
#pragma unroll
        for (int n = 0; n < WN; ++n) acc[m][n] = 0;

    for (int kb = 0; kb < K; kb += BK) {
        if (kb) __syncthreads();
#pragma unroll
        for (int i = 0; i < 4; ++i) {
            int r = wid * 32 + i * 8;
            gload16(A + (size_t)(m0 + r + l8) * K + kb + swz * 8, sA + r * BK);
        }
#pragma unroll
        for (int i = 0; i < BN / 32; ++i) {
            int r = wid * (BN / 4) + i * 8;
            gload16(BT + (size_t)(n0 + r + l8) * K + kb + swz * 8, sB + r * BK);
        }
        __syncthreads();

#pragma unroll
        for (int kk = 0; kk < BK; kk += 32) {
            int cb = (kk + kq) * 2;
            bf16x8 af[WM], bfr[WN];
#pragma unroll
            for (int m = 0; m < WM; ++m) {
                int r = wrow0 + m * 16 + lr;
                af[m] = __builtin_bit_cast(bf16x8,
                    *(const uint4*)((const char*)sA + r * 128 + (cb ^ ((r & 7) << 4))));
            }
#pragma unroll
            for (int n = 0; n < WN; ++n) {
                int r = wcol0 + n * 16 + lr;
                bfr[n] = __builtin_bit_cast(bf16x8,
                    *(const uint4*)((const char*)sB + r * 128 + (cb ^ ((r & 7) << 4))));
            }
#pragma unroll
            for (int m = 0; m < WM; ++m)
#pragma unroll
                for (int n = 0; n < WN; ++n)
                    acc[m][n] = __builtin_amdgcn_mfma_f32_16x16x32_bf16(
                        af[m], bfr[n], acc[m][n], 0, 0, 0);
        }
    }

    int rbase = m0 + wrow0 + ((lane >> 4) << 2);
#pragma unroll
    for (int n = 0; n < WN; ++n) {
        int col = n0 + wcol0 + n * 16 + lr;
        float bv = bias[col];
#pragma unroll
        for (int m = 0; m < WM; ++m) {
#pragma unroll
            for (int r = 0; r < 4; ++r) {
                int grow = rbase + m * 16 + r;
                if (grow < M) {
                    float v = acc[m][n][r] + bv;
                    if (RELU) v = fmaxf(v, 0.0f);
                    if (OUTF32) ((float*)Cout)[(size_t)grow * Nfull + col] = v;
                    else        ((ushort*)Cout)[(size_t)grow * Nfull + col] = f2bf(v);
                }
            }
        }
    }
}

// ---------------- launch ----------------

extern "C" void kernel_launch(void* const* d_in, const int* in_sizes, int n_in,
                              void* d_out, int out_size, void* d_ws, size_t ws_size,
                              hipStream_t stream) {
    const float* x  = (const float*)d_in[0];
    const int*   ei = (const int*)d_in[1];   // [2, 800000]: row0 = src, row1 = dst
    const float* W1 = (const float*)d_in[2];
    const float* b1 = (const float*)d_in[3];
    const float* W2 = (const float*)d_in[4];
    const float* b2 = (const float*)d_in[5];
    const float* Wc = (const float*)d_in[6];
    const float* bc = (const float*)d_in[7];
    float* out = (float*)d_out;

    // workspace carve (all segments 16B-aligned)
    char* p = (char*)d_ws;
    int* offs   = (int*)p; p += (N_NODES + 4) * 4;
    int* cursor = (int*)p; p += N_NODES * 4;
    int* cnt    = (int*)p; p += N_NODES * 4;
    int* tmp    = (int*)p; p += N_NODES * 4;
    int* bsum   = (int*)p; p += 256 * 4;
    int* elist  = (int*)p; p += N_EDGES * 4;
    ushort* W1T = (ushort*)p; p += 256 * 128 * 2;
    ushort* W2T = (ushort*)p; p += 256 * 256 * 2;
    ushort* WcT = (ushort*)p; p += 64 * 256 * 2;
    ushort* xb  = (ushort*)p; p += (size_t)N_NODES * 128 * 2;
    ushort* hsum = (ushort*)p; p += (size_t)M_PAD * 128 * 2;  // padded rows for staging
    ushort* h1  = (ushort*)p; p += (size_t)M_PAD * 256 * 2;
    ushort* h2  = (ushort*)p; p += (size_t)M_PAD * 256 * 2;

    hipMemsetAsync(cnt, 0, N_NODES * 4, stream);
    k_prep<<<NB_EDGE8 + NB_CAST + NB_TR, 256, 0, stream>>>(
        ei, cnt, x, xb, W1, W1T, W2, W2T, Wc, WcT);
    k_scan1<<<NB_SCAN, 256, 0, stream>>>(cnt, tmp, bsum);
    k_scan23<<<NB_SCAN, 256, 0, stream>>>(bsum, tmp, offs, cursor);
    k_scatter<<<NB_EDGE8, 256, 0, stream>>>(ei, cursor, elist);

    k_aggregate<<<N_NODES / 8, 256, 0, stream>>>(xb, offs, elist, hsum);

    const int MT = M_PAD / 128;  // 391
    dim3 g1(MT, 2), g2(MT, 2), g3(MT, 1);
    k_gemm2<128, 128, true,  false><<<g1, 256, 0, stream>>>(hsum, W1T, b1, h1, N_NODES, 256);
    k_gemm2<256, 128, true,  false><<<g2, 256, 0, stream>>>(h1,   W2T, b2, h2, N_NODES, 256);
    k_gemm2<256, 64,  false, true ><<<g3, 256, 0, stream>>>(h2,   WcT, bc, out, N_NODES, 64);
}

// Round 6
// 175.434 us; speedup vs baseline: 1.4832x; 1.2274x over previous
//
#include <hip/hip_runtime.h>
#include <hip/hip_bf16.h>

#define N_NODES 50000
#define M_PAD   50048   // 391 * 128, so GEMM staging never reads past allocations
#define N_EDGES 800000
#define NBUCK   391     // bucket = dst>>7 -> 128 nodes per bucket
#define NB_EB   391     // ceil(800000/2048), ILP-8 edge blocks
#define NB_CAST 3125    // 50000*128/8/256
#define NB_TR   448     // (128*256+256*256+256*64)/256

typedef __bf16 bf16x8 __attribute__((ext_vector_type(8)));
typedef float  f32x4  __attribute__((ext_vector_type(4)));

__device__ __forceinline__ ushort f2bf(float f) {
    __hip_bfloat16 h = __float2bfloat16(f);
    return __builtin_bit_cast(ushort, h);
}
__device__ __forceinline__ float bf2f(ushort u) {
    return __builtin_bit_cast(float, (unsigned)u << 16);
}

// async global->LDS, 16B per lane; lds base must be wave-uniform
__device__ __forceinline__ void gload16(const ushort* g, ushort* l) {
    __builtin_amdgcn_global_load_lds(
        (const __attribute__((address_space(1))) unsigned*)g,
        (__attribute__((address_space(3))) unsigned*)l, 16, 0, 0);
}

// ---------------- prep: x cast + weight transpose (no more global hist) ----------------
__device__ __forceinline__ void transpose_one(const float* W, ushort* WT,
                                              int K, int N, int t) {
    int k = t / N, n = t % N;
    WT[n * K + k] = f2bf(W[t]);
}

__global__ __launch_bounds__(256) void k_prep(const float* __restrict__ x,
                                              ushort* __restrict__ xb,
                                              const float* __restrict__ W1, ushort* __restrict__ W1T,
                                              const float* __restrict__ W2, ushort* __restrict__ W2T,
                                              const float* __restrict__ Wc, ushort* __restrict__ WcT) {
    int b = blockIdx.x, t = threadIdx.x;
    if (b < NB_CAST) {
        int i = b * 256 + t;  // 8 elems each
        const float4* x4 = (const float4*)x;
        float4 a = x4[(size_t)i * 2], bb = x4[(size_t)i * 2 + 1];
        ushort o[8];
        o[0] = f2bf(a.x); o[1] = f2bf(a.y); o[2] = f2bf(a.z); o[3] = f2bf(a.w);
        o[4] = f2bf(bb.x); o[5] = f2bf(bb.y); o[6] = f2bf(bb.z); o[7] = f2bf(bb.w);
        *(uint4*)(xb + (size_t)i * 8) = *(uint4*)o;
    } else {
        int tg = (b - NB_CAST) * 256 + t;
        const int S1 = 128 * 256, S2 = 256 * 256, S3 = 256 * 64;
        if (tg < S1) transpose_one(W1, W1T, 128, 256, tg);
        else if (tg < S1 + S2) transpose_one(W2, W2T, 256, 256, tg - S1);
        else if (tg < S1 + S2 + S3) transpose_one(Wc, WcT, 256, 64, tg - S1 - S2);
    }
}

// ---------------- bucketed CSR build ----------------
// pass 1: per-block LDS histogram over 391 buckets -> global bcnt
__global__ __launch_bounds__(256) void k_bhist(const int* __restrict__ ei,
                                               int* __restrict__ bcnt) {
    __shared__ int lh[NBUCK];
    int t = threadIdx.x;
    for (int i = t; i < NBUCK; i += 256) lh[i] = 0;
    __syncthreads();
    int base = blockIdx.x * 2048 + t;
#pragma unroll
    for (int k = 0; k < 8; ++k) {
        int e = base + k * 256;
        if (e < N_EDGES) atomicAdd(&lh[ei[N_EDGES + e] >> 7], 1);
    }
    __syncthreads();
    for (int i = t; i < NBUCK; i += 256) {
        int v = lh[i];
        if (v) atomicAdd(&bcnt[i], v);
    }
}

// pass 2: 1-block scan of bucket counts -> bboff (exclusive) + bcursor
__global__ __launch_bounds__(512) void k_bscan(const int* __restrict__ bcnt,
                                               int* __restrict__ bboff,
                                               int* __restrict__ bcursor) {
    __shared__ int ws[512];
    int t = threadIdx.x;
    int v = (t < NBUCK) ? bcnt[t] : 0;
    ws[t] = v;
    __syncthreads();
#pragma unroll
    for (int off = 1; off < 512; off <<= 1) {
        int u = (t >= off) ? ws[t - off] : 0;
        __syncthreads();
        ws[t] += u;
        __syncthreads();
    }
    if (t < NBUCK) {
        int e = ws[t] - v;
        bboff[t] = e;
        bcursor[t] = e;
    }
    if (t == 0) bboff[NBUCK] = N_EDGES;
}

// pass 3: scatter (src,dst) pairs into bucket-grouped pbuf; per-block LDS ranks,
// one chunk-reservation atomic per (block,bucket)
__global__ __launch_bounds__(256) void k_bscatter(const int* __restrict__ ei,
                                                  int* __restrict__ bcursor,
                                                  uint2* __restrict__ pbuf) {
    __shared__ int lh[NBUCK];
    __shared__ int lbase[NBUCK];
    int t = threadIdx.x;
    for (int i = t; i < NBUCK; i += 256) lh[i] = 0;
    __syncthreads();
    int base = blockIdx.x * 2048 + t;
    int s[8], d[8], bk[8], rk[8];
#pragma unroll
    for (int k = 0; k < 8; ++k) {
        int e = base + k * 256;
        bool ok = e < N_EDGES;
        int ee = ok ? e : 0;
        s[k] = ei[ee];
        d[k] = ei[N_EDGES + ee];
        bk[k] = ok ? (d[k] >> 7) : -1;
    }
#pragma unroll
    for (int k = 0; k < 8; ++k)
        if (bk[k] >= 0) rk[k] = atomicAdd(&lh[bk[k]], 1);
    __syncthreads();
    for (int i = t; i < NBUCK; i += 256) {
        int v = lh[i];
        lbase[i] = v ? atomicAdd(&bcursor[i], v) : 0;
    }
    __syncthreads();
#pragma unroll
    for (int k = 0; k < 8; ++k)
        if (bk[k] >= 0)
            pbuf[lbase[bk[k]] + rk[k]] = make_uint2((unsigned)s[k], (unsigned)d[k]);
}

// pass 4: one block per bucket: per-node LDS count/scan/place -> offs + elist
__global__ __launch_bounds__(256) void k_bplace(const uint2* __restrict__ pbuf,
                                                const int* __restrict__ bboff,
                                                int* __restrict__ offs,
                                                int* __restrict__ elist) {
    __shared__ int lcnt[128], lexc[128];
    int b = blockIdx.x, t = threadIdx.x;
    int s = bboff[b], m = bboff[b + 1] - s;
    if (t < 128) lcnt[t] = 0;
    __syncthreads();
    for (int i = t; i < m; i += 256)
        atomicAdd(&lcnt[pbuf[s + i].y & 127], 1);
    __syncthreads();
    if (t < 128) lexc[t] = lcnt[t];
    __syncthreads();
#pragma unroll
    for (int off = 1; off < 128; off <<= 1) {
        int u = (t < 128 && t >= off) ? lexc[t - off] : 0;
        __syncthreads();
        if (t < 128) lexc[t] += u;
        __syncthreads();
    }
    int n0 = b << 7;
    if (t < 128) {
        int excl = lexc[t] - lcnt[t];
        int node = n0 + t;
        if (node < N_NODES) offs[node] = s + excl;
        lcnt[t] = excl;  // becomes cursor
    }
    __syncthreads();
    for (int i = t; i < m; i += 256) {
        uint2 pr = pbuf[s + i];
        int pos = atomicAdd(&lcnt[pr.y & 127], 1);
        elist[s + pos] = (int)pr.x;
    }
    if (b == 0 && t == 0) offs[N_NODES] = N_EDGES;
}

// ---------------- aggregation (bf16 gather): hsum[i] = x[i] + sum_{j->i} x[j] ----------------
__global__ __launch_bounds__(256) void k_aggregate(const ushort* __restrict__ xb,
                                                   const int* __restrict__ offs,
                                                   const int* __restrict__ elist,
                                                   ushort* __restrict__ hsum) {
    int g = threadIdx.x >> 5, lane = threadIdx.x & 31;
    int node = blockIdx.x * 8 + g;
    if (node >= N_NODES) return;
    const ushort4* x4 = (const ushort4*)xb;
    ushort4 mine = x4[(size_t)node * 32 + lane];
    float acc0 = bf2f(mine.x), acc1 = bf2f(mine.y), acc2 = bf2f(mine.z), acc3 = bf2f(mine.w);
    int beg = offs[node], end = offs[node + 1];
    for (int base = beg; base < end; base += 32) {
        int m = end - base;
        int idx = 0;
        if (lane < m) idx = elist[base + lane];
        int c = m < 32 ? m : 32;
        for (int j = 0; j < c; ++j) {
            int s = __shfl(idx, j, 32);
            ushort4 v = x4[(size_t)s * 32 + lane];
            acc0 += bf2f(v.x); acc1 += bf2f(v.y); acc2 += bf2f(v.z); acc3 += bf2f(v.w);
        }
    }
    ushort4 o;
    o.x = f2bf(acc0); o.y = f2bf(acc1); o.z = f2bf(acc2); o.w = f2bf(acc3);
    *(ushort4*)(hsum + (size_t)node * 128 + lane * 4) = o;
}

// ---------------- m97-style bf16 MFMA GEMM ----------------
template <int K, int BN, bool RELU, bool OUTF32>
__global__ __launch_bounds__(256) void k_gemm2(const ushort* __restrict__ A,
                                               const ushort* __restrict__ BT,
                                               const float* __restrict__ bias,
                                               void* __restrict__ Cout,
                                               int M, int Nfull) {
    constexpr int BM = 128, BK = 64;
    constexpr int WAVES_N = (BN == 128) ? 2 : 1;
    constexpr int WMROWS = BM / (4 / WAVES_N);
    constexpr int WM = WMROWS / 16;
    constexpr int WN = (BN / WAVES_N) / 16;
    __shared__ ushort sA[BM * BK];
    __shared__ ushort sB[BN * BK];

    int m0 = blockIdx.x * BM, n0 = blockIdx.y * BN;
    int tid = threadIdx.x, wid = tid >> 6, lane = tid & 63;
    int lr = lane & 15;
    int kq = (lane >> 4) << 3;
    int l8 = lane >> 3, c8 = lane & 7;
    int swz = c8 ^ l8;

    int wrow0 = (wid / WAVES_N) * WMROWS;
    int wcol0 = (wid % WAVES_N) * 64;

    f32x4 acc[WM][WN];
#pragma unroll
    for (int m = 0; m < WM; ++m)
#pragma unroll
        for (int n = 0; n < WN; ++n) acc[m][n] = 0;

    for (int kb = 0; kb < K; kb += BK) {
        if (kb) __syncthreads();
#pragma unroll
        for (int i = 0; i < 4; ++i) {
            int r = wid * 32 + i * 8;
            gload16(A + (size_t)(m0 + r + l8) * K + kb + swz * 8, sA + r * BK);
        }
#pragma unroll
        for (int i = 0; i < BN / 32; ++i) {
            int r = wid * (BN / 4) + i * 8;
            gload16(BT + (size_t)(n0 + r + l8) * K + kb + swz * 8, sB + r * BK);
        }
        __syncthreads();

#pragma unroll
        for (int kk = 0; kk < BK; kk += 32) {
            int cb = (kk + kq) * 2;
            bf16x8 af[WM], bfr[WN];
#pragma unroll
            for (int m = 0; m < WM; ++m) {
                int r = wrow0 + m * 16 + lr;
                af[m] = __builtin_bit_cast(bf16x8,
                    *(const uint4*)((const char*)sA + r * 128 + (cb ^ ((r & 7) << 4))));
            }
#pragma unroll
            for (int n = 0; n < WN; ++n) {
                int r = wcol0 + n * 16 + lr;
                bfr[n] = __builtin_bit_cast(bf16x8,
                    *(const uint4*)((const char*)sB + r * 128 + (cb ^ ((r & 7) << 4))));
            }
#pragma unroll
            for (int m = 0; m < WM; ++m)
#pragma unroll
                for (int n = 0; n < WN; ++n)
                    acc[m][n] = __builtin_amdgcn_mfma_f32_16x16x32_bf16(
                        af[m], bfr[n], acc[m][n], 0, 0, 0);
        }
    }

    int rbase = m0 + wrow0 + ((lane >> 4) << 2);
#pragma unroll
    for (int n = 0; n < WN; ++n) {
        int col = n0 + wcol0 + n * 16 + lr;
        float bv = bias[col];
#pragma unroll
        for (int m = 0; m < WM; ++m) {
#pragma unroll
            for (int r = 0; r < 4; ++r) {
                int grow = rbase + m * 16 + r;
                if (grow < M) {
                    float v = acc[m][n][r] + bv;
                    if (RELU) v = fmaxf(v, 0.0f);
                    if (OUTF32) ((float*)Cout)[(size_t)grow * Nfull + col] = v;
                    else        ((ushort*)Cout)[(size_t)grow * Nfull + col] = f2bf(v);
                }
            }
        }
    }
}

// ---------------- launch ----------------

extern "C" void kernel_launch(void* const* d_in, const int* in_sizes, int n_in,
                              void* d_out, int out_size, void* d_ws, size_t ws_size,
                              hipStream_t stream) {
    const float* x  = (const float*)d_in[0];
    const int*   ei = (const int*)d_in[1];   // [2, 800000]: row0 = src, row1 = dst
    const float* W1 = (const float*)d_in[2];
    const float* b1 = (const float*)d_in[3];
    const float* W2 = (const float*)d_in[4];
    const float* b2 = (const float*)d_in[5];
    const float* Wc = (const float*)d_in[6];
    const float* bc = (const float*)d_in[7];
    float* out = (float*)d_out;

    // workspace carve (all segments 16B-aligned via padded counts)
    char* p = (char*)d_ws;
    int* offs    = (int*)p; p += 50008 * 4;
    int* bcnt    = (int*)p; p += 400 * 4;
    int* bboff   = (int*)p; p += 400 * 4;
    int* bcursor = (int*)p; p += 400 * 4;
    int* elist   = (int*)p; p += N_EDGES * 4;
    uint2* pbuf  = (uint2*)p; p += (size_t)N_EDGES * 8;
    ushort* W1T = (ushort*)p; p += 256 * 128 * 2;
    ushort* W2T = (ushort*)p; p += 256 * 256 * 2;
    ushort* WcT = (ushort*)p; p += 64 * 256 * 2;
    ushort* xb  = (ushort*)p; p += (size_t)N_NODES * 128 * 2;
    ushort* hsum = (ushort*)p; p += (size_t)M_PAD * 128 * 2;  // padded rows for staging
    ushort* h1  = (ushort*)p; p += (size_t)M_PAD * 256 * 2;
    ushort* h2  = (ushort*)p; p += (size_t)M_PAD * 256 * 2;

    hipMemsetAsync(bcnt, 0, 400 * 4, stream);
    k_prep<<<NB_CAST + NB_TR, 256, 0, stream>>>(x, xb, W1, W1T, W2, W2T, Wc, WcT);
    k_bhist<<<NB_EB, 256, 0, stream>>>(ei, bcnt);
    k_bscan<<<1, 512, 0, stream>>>(bcnt, bboff, bcursor);
    k_bscatter<<<NB_EB, 256, 0, stream>>>(ei, bcursor, pbuf);
    k_bplace<<<NBUCK, 256, 0, stream>>>(pbuf, bboff, offs, elist);

    k_aggregate<<<N_NODES / 8, 256, 0, stream>>>(xb, offs, elist, hsum);

    const int MT = M_PAD / 128;  // 391
    dim3 g1(MT, 2), g2(MT, 2), g3(MT, 1);
    k_gemm2<128, 128, true,  false><<<g1, 256, 0, stream>>>(hsum, W1T, b1, h1, N_NODES, 256);
    k_gemm2<256, 128, true,  false><<<g2, 256, 0, stream>>>(h1,   W2T, b2, h2, N_NODES, 256);
    k_gemm2<256, 64,  false, true ><<<g3, 256, 0, stream>>>(h2,   WcT, bc, out, N_NODES, 64);
}

// Round 7
// 125.746 us; speedup vs baseline: 2.0692x; 1.3951x over previous
//
#include <hip/hip_runtime.h>
#include <hip/hip_bf16.h>

#define N_NODES 50000
#define M_PAD   50048   // 391 * 128
#define N_EDGES 800000
#define NBUCK   391     // bucket = dst>>7 -> 128 nodes per bucket
#define NB_EB   391     // ceil(800000/2048), ILP-8 edge blocks
#define NB_CAST 3125    // 50000*128/8/256
#define NB_TR   448     // (128*256+256*256+256*64)/256

typedef __bf16 bf16x8 __attribute__((ext_vector_type(8)));
typedef float  f32x4  __attribute__((ext_vector_type(4)));

__device__ __forceinline__ ushort f2bf(float f) {
    __hip_bfloat16 h = __float2bfloat16(f);
    return __builtin_bit_cast(ushort, h);
}
__device__ __forceinline__ float bf2f(ushort u) {
    return __builtin_bit_cast(float, (unsigned)u << 16);
}

// async global->LDS, 16B per lane; lds base must be wave-uniform
__device__ __forceinline__ void gload16(const ushort* g, ushort* l) {
    __builtin_amdgcn_global_load_lds(
        (const __attribute__((address_space(1))) unsigned*)g,
        (__attribute__((address_space(3))) unsigned*)l, 16, 0, 0);
}

// ---------------- prep: x cast + weight transpose ----------------
__device__ __forceinline__ void transpose_one(const float* W, ushort* WT,
                                              int K, int N, int t) {
    int k = t / N, n = t % N;
    WT[n * K + k] = f2bf(W[t]);
}

__global__ __launch_bounds__(256) void k_prep(const float* __restrict__ x,
                                              ushort* __restrict__ xb,
                                              const float* __restrict__ W1, ushort* __restrict__ W1T,
                                              const float* __restrict__ W2, ushort* __restrict__ W2T,
                                              const float* __restrict__ Wc, ushort* __restrict__ WcT) {
    int b = blockIdx.x, t = threadIdx.x;
    if (b < NB_CAST) {
        int i = b * 256 + t;  // 8 elems each
        const float4* x4 = (const float4*)x;
        float4 a = x4[(size_t)i * 2], bb = x4[(size_t)i * 2 + 1];
        ushort o[8];
        o[0] = f2bf(a.x); o[1] = f2bf(a.y); o[2] = f2bf(a.z); o[3] = f2bf(a.w);
        o[4] = f2bf(bb.x); o[5] = f2bf(bb.y); o[6] = f2bf(bb.z); o[7] = f2bf(bb.w);
        *(uint4*)(xb + (size_t)i * 8) = *(uint4*)o;
    } else {
        int tg = (b - NB_CAST) * 256 + t;
        const int S1 = 128 * 256, S2 = 256 * 256, S3 = 256 * 64;
        if (tg < S1) transpose_one(W1, W1T, 128, 256, tg);
        else if (tg < S1 + S2) transpose_one(W2, W2T, 256, 256, tg - S1);
        else if (tg < S1 + S2 + S3) transpose_one(Wc, WcT, 256, 64, tg - S1 - S2);
    }
}

// ---------------- bucketed CSR build ----------------
__global__ __launch_bounds__(256) void k_bhist(const int* __restrict__ ei,
                                               int* __restrict__ bcnt) {
    __shared__ int lh[NBUCK];
    int t = threadIdx.x;
    for (int i = t; i < NBUCK; i += 256) lh[i] = 0;
    __syncthreads();
    int base = blockIdx.x * 2048 + t;
#pragma unroll
    for (int k = 0; k < 8; ++k) {
        int e = base + k * 256;
        if (e < N_EDGES) atomicAdd(&lh[ei[N_EDGES + e] >> 7], 1);
    }
    __syncthreads();
    for (int i = t; i < NBUCK; i += 256) {
        int v = lh[i];
        if (v) atomicAdd(&bcnt[i], v);
    }
}

__global__ __launch_bounds__(512) void k_bscan(const int* __restrict__ bcnt,
                                               int* __restrict__ bboff,
                                               int* __restrict__ bcursor) {
    __shared__ int ws[512];
    int t = threadIdx.x;
    int v = (t < NBUCK) ? bcnt[t] : 0;
    ws[t] = v;
    __syncthreads();
#pragma unroll
    for (int off = 1; off < 512; off <<= 1) {
        int u = (t >= off) ? ws[t - off] : 0;
        __syncthreads();
        ws[t] += u;
        __syncthreads();
    }
    if (t < NBUCK) {
        int e = ws[t] - v;
        bboff[t] = e;
        bcursor[t] = e;
    }
    if (t == 0) bboff[NBUCK] = N_EDGES;
}

__global__ __launch_bounds__(256) void k_bscatter(const int* __restrict__ ei,
                                                  int* __restrict__ bcursor,
                                                  uint2* __restrict__ pbuf) {
    __shared__ int lh[NBUCK];
    __shared__ int lbase[NBUCK];
    int t = threadIdx.x;
    for (int i = t; i < NBUCK; i += 256) lh[i] = 0;
    __syncthreads();
    int base = blockIdx.x * 2048 + t;
    int s[8], d[8], bk[8], rk[8];
#pragma unroll
    for (int k = 0; k < 8; ++k) {
        int e = base + k * 256;
        bool ok = e < N_EDGES;
        int ee = ok ? e : 0;
        s[k] = ei[ee];
        d[k] = ei[N_EDGES + ee];
        bk[k] = ok ? (d[k] >> 7) : -1;
    }
#pragma unroll
    for (int k = 0; k < 8; ++k)
        if (bk[k] >= 0) rk[k] = atomicAdd(&lh[bk[k]], 1);
    __syncthreads();
    for (int i = t; i < NBUCK; i += 256) {
        int v = lh[i];
        lbase[i] = v ? atomicAdd(&bcursor[i], v) : 0;
    }
    __syncthreads();
#pragma unroll
    for (int k = 0; k < 8; ++k)
        if (bk[k] >= 0)
            pbuf[lbase[bk[k]] + rk[k]] = make_uint2((unsigned)s[k], (unsigned)d[k]);
}

__global__ __launch_bounds__(256) void k_bplace(const uint2* __restrict__ pbuf,
                                                const int* __restrict__ bboff,
                                                int* __restrict__ offs,
                                                int* __restrict__ elist) {
    __shared__ int lcnt[128], lexc[128];
    int b = blockIdx.x, t = threadIdx.x;
    int s = bboff[b], m = bboff[b + 1] - s;
    if (t < 128) lcnt[t] = 0;
    __syncthreads();
    for (int i = t; i < m; i += 256)
        atomicAdd(&lcnt[pbuf[s + i].y & 127], 1);
    __syncthreads();
    if (t < 128) lexc[t] = lcnt[t];
    __syncthreads();
#pragma unroll
    for (int off = 1; off < 128; off <<= 1) {
        int u = (t < 128 && t >= off) ? lexc[t - off] : 0;
        __syncthreads();
        if (t < 128) lexc[t] += u;
        __syncthreads();
    }
    int n0 = b << 7;
    if (t < 128) {
        int excl = lexc[t] - lcnt[t];
        int node = n0 + t;
        if (node < N_NODES) offs[node] = s + excl;
        lcnt[t] = excl;  // becomes cursor
    }
    __syncthreads();
    for (int i = t; i < m; i += 256) {
        uint2 pr = pbuf[s + i];
        int pos = atomicAdd(&lcnt[pr.y & 127], 1);
        elist[s + pos] = (int)pr.x;
    }
    if (b == 0 && t == 0) offs[N_NODES] = N_EDGES;
}

// ---------------- aggregation: batch-8 gather ILP ----------------
__global__ __launch_bounds__(256) void k_aggregate(const ushort* __restrict__ xb,
                                                   const int* __restrict__ offs,
                                                   const int* __restrict__ elist,
                                                   ushort* __restrict__ hsum) {
    int g = threadIdx.x >> 5, lane = threadIdx.x & 31;
    int node = blockIdx.x * 8 + g;
    if (node >= N_NODES) return;
    const ushort4* x4 = (const ushort4*)xb;
    ushort4 mine = x4[(size_t)node * 32 + lane];
    float acc0 = bf2f(mine.x), acc1 = bf2f(mine.y), acc2 = bf2f(mine.z), acc3 = bf2f(mine.w);
    int beg = offs[node], end = offs[node + 1];
    for (int base = beg; base < end; base += 32) {
        int m = end - base;
        int idx = (lane < m) ? elist[base + lane] : 0;
        int c = m < 32 ? m : 32;
        int j = 0;
        for (; j + 8 <= c; j += 8) {
            ushort4 v[8];
#pragma unroll
            for (int u = 0; u < 8; ++u) {
                int s = __shfl(idx, j + u, 32);
                v[u] = x4[(size_t)s * 32 + lane];
            }
#pragma unroll
            for (int u = 0; u < 8; ++u) {
                acc0 += bf2f(v[u].x); acc1 += bf2f(v[u].y);
                acc2 += bf2f(v[u].z); acc3 += bf2f(v[u].w);
            }
        }
        for (; j < c; ++j) {
            int s = __shfl(idx, j, 32);
            ushort4 v = x4[(size_t)s * 32 + lane];
            acc0 += bf2f(v.x); acc1 += bf2f(v.y); acc2 += bf2f(v.z); acc3 += bf2f(v.w);
        }
    }
    ushort4 o;
    o.x = f2bf(acc0); o.y = f2bf(acc1); o.z = f2bf(acc2); o.w = f2bf(acc3);
    *(ushort4*)(hsum + (size_t)node * 128 + lane * 4) = o;
}

// ---------------- fully-fused 3-stage MLP ----------------
// 512 threads (8 waves), 128-row stripe per block.
// LDS: sA[128x64] (16KB) + sB[256x64] (32KB) + ht[128x256] (64KB, XOR-swizzled).
__global__ __launch_bounds__(512) void k_mlp3(const ushort* __restrict__ hsum,
                                              const ushort* __restrict__ W1T,
                                              const float* __restrict__ b1,
                                              const ushort* __restrict__ W2T,
                                              const float* __restrict__ b2,
                                              const ushort* __restrict__ WcT,
                                              const float* __restrict__ bc,
                                              float* __restrict__ out, int M) {
    __shared__ ushort sA[128 * 64];
    __shared__ ushort sB[256 * 64];
    __shared__ ushort ht[128 * 256];

    int m0 = blockIdx.x * 128;
    int tid = threadIdx.x, wv = tid >> 6, lane = tid & 63;
    int lr = lane & 15;
    int kq = (lane >> 4) << 3;
    int l8 = (lane >> 3) & 7, c8 = lane & 7;
    int swz8 = c8 ^ l8;

    int wrow0 = (wv >> 2) * 64;   // stage1/2 wave grid: 2M x 4N, 64x64 per wave
    int wcol0 = (wv & 3) * 64;
    int crow = (lane >> 4) << 2;

    f32x4 acc[4][4];

    // ======== stage 1: h1 = relu(hsum @ W1 + b1), K=128 ========
#pragma unroll
    for (int m = 0; m < 4; ++m)
#pragma unroll
        for (int n = 0; n < 4; ++n) acc[m][n] = 0;

    for (int kb = 0; kb < 128; kb += 64) {
#pragma unroll
        for (int i = 0; i < 2; ++i) {
            int rg = i * 64 + wv * 8;
            gload16(hsum + (size_t)(m0 + rg + l8) * 128 + kb + swz8 * 8, sA + rg * 64);
        }
#pragma unroll
        for (int i = 0; i < 4; ++i) {
            int rg = i * 64 + wv * 8;
            gload16(W1T + (size_t)(rg + l8) * 128 + kb + swz8 * 8, sB + rg * 64);
        }
        __syncthreads();
#pragma unroll
        for (int kk = 0; kk < 64; kk += 32) {
            int cb = (kk + kq) * 2;
            bf16x8 af[4], bfr[4];
#pragma unroll
            for (int m = 0; m < 4; ++m) {
                int r = wrow0 + m * 16 + lr;
                af[m] = __builtin_bit_cast(bf16x8,
                    *(const uint4*)((const char*)sA + r * 128 + (cb ^ ((r & 7) << 4))));
            }
#pragma unroll
            for (int n = 0; n < 4; ++n) {
                int r = wcol0 + n * 16 + lr;
                bfr[n] = __builtin_bit_cast(bf16x8,
                    *(const uint4*)((const char*)sB + r * 128 + (cb ^ ((r & 7) << 4))));
            }
#pragma unroll
            for (int m = 0; m < 4; ++m)
#pragma unroll
                for (int n = 0; n < 4; ++n)
                    acc[m][n] = __builtin_amdgcn_mfma_f32_16x16x32_bf16(
                        af[m], bfr[n], acc[m][n], 0, 0, 0);
        }
        __syncthreads();
    }
#pragma unroll
    for (int n = 0; n < 4; ++n) {
        int col = wcol0 + n * 16 + lr;
        float bv = b1[col];
#pragma unroll
        for (int m = 0; m < 4; ++m) {
#pragma unroll
            for (int r = 0; r < 4; ++r) {
                int row = wrow0 + m * 16 + crow + r;
                int sc = ((((col >> 3) ^ (row & 7)) << 3) | (col & 7));
                ht[row * 256 + sc] = f2bf(fmaxf(acc[m][n][r] + bv, 0.0f));
            }
        }
    }
    __syncthreads();

    // ======== stage 2: h2 = relu(h1 @ W2 + b2), K=256 ========
#pragma unroll
    for (int m = 0; m < 4; ++m)
#pragma unroll
        for (int n = 0; n < 4; ++n) acc[m][n] = 0;

    for (int kb = 0; kb < 256; kb += 64) {
#pragma unroll
        for (int i = 0; i < 4; ++i) {
            int rg = i * 64 + wv * 8;
            gload16(W2T + (size_t)(rg + l8) * 256 + kb + swz8 * 8, sB + rg * 64);
        }
        __syncthreads();
#pragma unroll
        for (int kk = 0; kk < 64; kk += 32) {
            int cc = kb + kk + kq;
            int cb = (kk + kq) * 2;
            bf16x8 af[4], bfr[4];
#pragma unroll
            for (int m = 0; m < 4; ++m) {
                int r = wrow0 + m * 16 + lr;
                af[m] = __builtin_bit_cast(bf16x8,
                    *(const uint4*)(ht + r * 256 + ((((cc >> 3) ^ (r & 7)) << 3))));
            }
#pragma unroll
            for (int n = 0; n < 4; ++n) {
                int r = wcol0 + n * 16 + lr;
                bfr[n] = __builtin_bit_cast(bf16x8,
                    *(const uint4*)((const char*)sB + r * 128 + (cb ^ ((r & 7) << 4))));
            }
#pragma unroll
            for (int m = 0; m < 4; ++m)
#pragma unroll
                for (int n = 0; n < 4; ++n)
                    acc[m][n] = __builtin_amdgcn_mfma_f32_16x16x32_bf16(
                        af[m], bfr[n], acc[m][n], 0, 0, 0);
        }
        __syncthreads();
    }
    // epilogue 2: overwrite ht with relu(h2); also stage WcT into sB
#pragma unroll
    for (int n = 0; n < 4; ++n) {
        int col = wcol0 + n * 16 + lr;
        float bv = b2[col];
#pragma unroll
        for (int m = 0; m < 4; ++m) {
#pragma unroll
            for (int r = 0; r < 4; ++r) {
                int row = wrow0 + m * 16 + crow + r;
                int sc = ((((col >> 3) ^ (row & 7)) << 3) | (col & 7));
                ht[row * 256 + sc] = f2bf(fmaxf(acc[m][n][r] + bv, 0.0f));
            }
        }
    }
#pragma unroll
    for (int i = 0; i < 4; ++i)
        gload16(WcT + (size_t)(wv * 8 + l8) * 256 + i * 64 + swz8 * 8,
                sB + i * 4096 + wv * 8 * 64);
    __syncthreads();

    // ======== stage 3: out = h2 @ Wc + bc, K=256, N=64 ========
    f32x4 acc3[4];
#pragma unroll
    for (int n = 0; n < 4; ++n) acc3[n] = 0;
    int arow3 = wv * 16 + lr;   // 8 waves x 16 rows
#pragma unroll
    for (int kb4 = 0; kb4 < 4; ++kb4) {
#pragma unroll
        for (int kk = 0; kk < 64; kk += 32) {
            int cc = kb4 * 64 + kk + kq;
            int cb = (kk + kq) * 2;
            bf16x8 a = __builtin_bit_cast(bf16x8,
                *(const uint4*)(ht + arow3 * 256 + ((((cc >> 3) ^ (arow3 & 7)) << 3))));
#pragma unroll
            for (int n = 0; n < 4; ++n) {
                int r = n * 16 + lr;
                bf16x8 b = __builtin_bit_cast(bf16x8,
                    *(const uint4*)((const char*)sB + kb4 * 8192 + r * 128 +
                                    (cb ^ ((r & 7) << 4))));
                acc3[n] = __builtin_amdgcn_mfma_f32_16x16x32_bf16(a, b, acc3[n], 0, 0, 0);
            }
        }
    }
#pragma unroll
    for (int n = 0; n < 4; ++n) {
        int col = n * 16 + lr;
        float bv = bc[col];
#pragma unroll
        for (int r = 0; r < 4; ++r) {
            int grow = m0 + wv * 16 + crow + r;
            if (grow < M) out[(size_t)grow * 64 + col] = acc3[n][r] + bv;
        }
    }
}

// ---------------- launch ----------------

extern "C" void kernel_launch(void* const* d_in, const int* in_sizes, int n_in,
                              void* d_out, int out_size, void* d_ws, size_t ws_size,
                              hipStream_t stream) {
    const float* x  = (const float*)d_in[0];
    const int*   ei = (const int*)d_in[1];   // [2, 800000]: row0 = src, row1 = dst
    const float* W1 = (const float*)d_in[2];
    const float* b1 = (const float*)d_in[3];
    const float* W2 = (const float*)d_in[4];
    const float* b2 = (const float*)d_in[5];
    const float* Wc = (const float*)d_in[6];
    const float* bc = (const float*)d_in[7];
    float* out = (float*)d_out;

    char* p = (char*)d_ws;
    int* offs    = (int*)p; p += 50008 * 4;
    int* bcnt    = (int*)p; p += 400 * 4;
    int* bboff   = (int*)p; p += 400 * 4;
    int* bcursor = (int*)p; p += 400 * 4;
    int* elist   = (int*)p; p += N_EDGES * 4;
    uint2* pbuf  = (uint2*)p; p += (size_t)N_EDGES * 8;
    ushort* W1T = (ushort*)p; p += 256 * 128 * 2;
    ushort* W2T = (ushort*)p; p += 256 * 256 * 2;
    ushort* WcT = (ushort*)p; p += 64 * 256 * 2;
    ushort* xb  = (ushort*)p; p += (size_t)N_NODES * 128 * 2;
    ushort* hsum = (ushort*)p; p += (size_t)M_PAD * 128 * 2;

    hipMemsetAsync(bcnt, 0, 400 * 4, stream);
    k_prep<<<NB_CAST + NB_TR, 256, 0, stream>>>(x, xb, W1, W1T, W2, W2T, Wc, WcT);
    k_bhist<<<NB_EB, 256, 0, stream>>>(ei, bcnt);
    k_bscan<<<1, 512, 0, stream>>>(bcnt, bboff, bcursor);
    k_bscatter<<<NB_EB, 256, 0, stream>>>(ei, bcursor, pbuf);
    k_bplace<<<NBUCK, 256, 0, stream>>>(pbuf, bboff, offs, elist);
    k_aggregate<<<N_NODES / 8, 256, 0, stream>>>(xb, offs, elist, hsum);
    k_mlp3<<<M_PAD / 128, 512, 0, stream>>>(hsum, W1T, b1, W2T, b2, WcT, bc, out, N_NODES);
}

// Round 8
// 122.440 us; speedup vs baseline: 2.1251x; 1.0270x over previous
//
#include <hip/hip_runtime.h>
#include <hip/hip_bf16.h>

#define N_NODES 50000
#define M_PAD   50048   // 391 * 128
#define N_EDGES 800000
#define NBUCK   391     // bucket = dst>>7 -> 128 nodes per bucket
#define NB_EB   391     // ceil(800000/2048)
#define NB_CAST 3125    // 50000*128/8/256
#define NB_TR   448     // (128*256+256*256+256*64)/256
#define EBMAX   4096    // per-bucket LDS edge cap (actual max ~2200)

typedef __bf16 bf16x8 __attribute__((ext_vector_type(8)));
typedef float  f32x4  __attribute__((ext_vector_type(4)));

__device__ __forceinline__ ushort f2bf(float f) {
    __hip_bfloat16 h = __float2bfloat16(f);
    return __builtin_bit_cast(ushort, h);
}
__device__ __forceinline__ float bf2f(ushort u) {
    return __builtin_bit_cast(float, (unsigned)u << 16);
}

// async global->LDS, 16B per lane; lds base must be wave-uniform
__device__ __forceinline__ void gload16(const ushort* g, ushort* l) {
    __builtin_amdgcn_global_load_lds(
        (const __attribute__((address_space(1))) unsigned*)g,
        (__attribute__((address_space(3))) unsigned*)l, 16, 0, 0);
}

// ---------------- prep: x cast + weight transpose + counter zeroing ----------------
__device__ __forceinline__ void transpose_one(const float* W, ushort* WT,
                                              int K, int N, int t) {
    int k = t / N, n = t % N;
    WT[n * K + k] = f2bf(W[t]);
}

__global__ __launch_bounds__(256) void k_prep(const float* __restrict__ x,
                                              ushort* __restrict__ xb,
                                              const float* __restrict__ W1, ushort* __restrict__ W1T,
                                              const float* __restrict__ W2, ushort* __restrict__ W2T,
                                              const float* __restrict__ Wc, ushort* __restrict__ WcT,
                                              int* __restrict__ bcnt, int* __restrict__ bcur0) {
    int b = blockIdx.x, t = threadIdx.x;
    if (b < NB_CAST) {
        int i = b * 256 + t;  // 8 elems each
        const float4* x4 = (const float4*)x;
        float4 a = x4[(size_t)i * 2], bb = x4[(size_t)i * 2 + 1];
        ushort o[8];
        o[0] = f2bf(a.x); o[1] = f2bf(a.y); o[2] = f2bf(a.z); o[3] = f2bf(a.w);
        o[4] = f2bf(bb.x); o[5] = f2bf(bb.y); o[6] = f2bf(bb.z); o[7] = f2bf(bb.w);
        *(uint4*)(xb + (size_t)i * 8) = *(uint4*)o;
    } else if (b < NB_CAST + NB_TR) {
        int tg = (b - NB_CAST) * 256 + t;
        const int S1 = 128 * 256, S2 = 256 * 256, S3 = 256 * 64;
        if (tg < S1) transpose_one(W1, W1T, 128, 256, tg);
        else if (tg < S1 + S2) transpose_one(W2, W2T, 256, 256, tg - S1);
        else if (tg < S1 + S2 + S3) transpose_one(Wc, WcT, 256, 64, tg - S1 - S2);
    } else {
        for (int i = t; i < 400; i += 256) { bcnt[i] = 0; bcur0[i] = 0; }
    }
}

// ---------------- bucket histogram: LDS-local then one atomic per bin ----------------
__global__ __launch_bounds__(256) void k_bhist(const int* __restrict__ ei,
                                               int* __restrict__ bcnt) {
    __shared__ int lh[NBUCK];
    int t = threadIdx.x;
    for (int i = t; i < NBUCK; i += 256) lh[i] = 0;
    __syncthreads();
    int base = blockIdx.x * 2048 + t;
#pragma unroll
    for (int k = 0; k < 8; ++k) {
        int e = base + k * 256;
        if (e < N_EDGES) atomicAdd(&lh[ei[N_EDGES + e] >> 7], 1);
    }
    __syncthreads();
    for (int i = t; i < NBUCK; i += 256) {
        int v = lh[i];
        if (v) atomicAdd(&bcnt[i], v);
    }
}

// ---------------- bucket scatter: in-LDS global scan + chunk reservation ----------------
__global__ __launch_bounds__(512) void k_bscatter(const int* __restrict__ ei,
                                                  const int* __restrict__ bcnt,
                                                  int* __restrict__ bcur0,
                                                  uint2* __restrict__ pbuf) {
    __shared__ int lh[NBUCK];
    __shared__ int lbase[NBUCK];
    __shared__ int ws[512];
    int t = threadIdx.x;
    for (int i = t; i < NBUCK; i += 512) lh[i] = 0;
    __syncthreads();
    int base = blockIdx.x * 2048 + t;
    int s[4], d[4], bk[4], rk[4];
#pragma unroll
    for (int k = 0; k < 4; ++k) {
        int e = base + k * 512;
        bool ok = e < N_EDGES;
        int ee = ok ? e : 0;
        s[k] = ei[ee];
        d[k] = ei[N_EDGES + ee];
        bk[k] = ok ? (d[k] >> 7) : -1;
    }
#pragma unroll
    for (int k = 0; k < 4; ++k)
        if (bk[k] >= 0) rk[k] = atomicAdd(&lh[bk[k]], 1);
    __syncthreads();
    // redundant in-LDS exclusive scan of global bcnt
    ws[t] = (t < NBUCK) ? bcnt[t] : 0;
    __syncthreads();
#pragma unroll
    for (int off = 1; off < 512; off <<= 1) {
        int u = (t >= off) ? ws[t - off] : 0;
        __syncthreads();
        ws[t] += u;
        __syncthreads();
    }
    if (t < NBUCK) {
        int v = lh[t];
        int excl = ws[t] - bcnt[t];
        lbase[t] = excl + (v ? atomicAdd(&bcur0[t], v) : 0);
    }
    __syncthreads();
#pragma unroll
    for (int k = 0; k < 4; ++k)
        if (bk[k] >= 0)
            pbuf[lbase[bk[k]] + rk[k]] = make_uint2((unsigned)s[k], (unsigned)d[k]);
}

// ---------------- fused place+aggregate: one block per bucket ----------------
// Builds the 128-node adjacency in LDS straight from pbuf, then gathers
// with batch-8 ILP and writes hsum rows.
__global__ __launch_bounds__(256) void k_agg2(const uint2* __restrict__ pbuf,
                                              const int* __restrict__ bcnt,
                                              const ushort* __restrict__ xb,
                                              ushort* __restrict__ hsum) {
    __shared__ int eb[EBMAX];
    __shared__ int red[256];
    __shared__ int lcnt[128], lexc[128], lcur[128];
    int b = blockIdx.x, t = threadIdx.x;

    // s = sum(bcnt[0..b))  (strided partial + tree reduce)
    int a = 0;
    for (int i = t; i < b; i += 256) a += bcnt[i];
    red[t] = a;
    __syncthreads();
#pragma unroll
    for (int off = 128; off >= 1; off >>= 1) {
        if (t < off) red[t] += red[t + off];
        __syncthreads();
    }
    int s = red[0];
    int m = bcnt[b]; if (m > EBMAX) m = EBMAX;

    // per-node counts
    if (t < 128) lcnt[t] = 0;
    __syncthreads();
    for (int i = t; i < m; i += 256)
        atomicAdd(&lcnt[pbuf[s + i].y & 127], 1);
    __syncthreads();
    if (t < 128) lexc[t] = lcnt[t];
    __syncthreads();
#pragma unroll
    for (int off = 1; off < 128; off <<= 1) {
        int u = (t < 128 && t >= off) ? lexc[t - off] : 0;
        __syncthreads();
        if (t < 128) lexc[t] += u;
        __syncthreads();
    }
    if (t < 128) {
        int e = lexc[t] - lcnt[t];
        lexc[t] = e;
        lcur[t] = e;
    }
    __syncthreads();
    for (int i = t; i < m; i += 256) {
        uint2 pr = pbuf[s + i];
        int pos = atomicAdd(&lcur[pr.y & 127], 1);
        if (pos < EBMAX) eb[pos] = (int)pr.x;
    }
    __syncthreads();

    // gather phase: 8 groups of 32 lanes; each group handles 16 nodes
    int g = t >> 5, lane = t & 31;
    const ushort4* x4 = (const ushort4*)xb;
    for (int nd = g; nd < 128; nd += 8) {
        int node = (b << 7) + nd;
        if (node >= N_NODES) continue;   // uniform per group
        int st = lexc[nd], cnt = lcnt[nd];
        ushort4 mine = x4[(size_t)node * 32 + lane];
        float a0 = bf2f(mine.x), a1 = bf2f(mine.y), a2 = bf2f(mine.z), a3 = bf2f(mine.w);
        for (int j = 0; j < cnt; j += 8) {
            ushort4 v[8];
#pragma unroll
            for (int u = 0; u < 8; ++u) {
                int q = j + u;
                bool ok = q < cnt;       // uniform per group
                int sidx = ok ? eb[st + q] : 0;
                if (ok) v[u] = x4[(size_t)sidx * 32 + lane];
                else    v[u] = make_ushort4(0, 0, 0, 0);
            }
#pragma unroll
            for (int u = 0; u < 8; ++u) {
                a0 += bf2f(v[u].x); a1 += bf2f(v[u].y);
                a2 += bf2f(v[u].z); a3 += bf2f(v[u].w);
            }
        }
        ushort4 o;
        o.x = f2bf(a0); o.y = f2bf(a1); o.z = f2bf(a2); o.w = f2bf(a3);
        *(ushort4*)(hsum + (size_t)node * 128 + lane * 4) = o;
    }
}

// ---------------- fully-fused 3-stage MLP (unchanged from R7) ----------------
__global__ __launch_bounds__(512) void k_mlp3(const ushort* __restrict__ hsum,
                                              const ushort* __restrict__ W1T,
                                              const float* __restrict__ b1,
                                              const ushort* __restrict__ W2T,
                                              const float* __restrict__ b2,
                                              const ushort* __restrict__ WcT,
                                              const float* __restrict__ bc,
                                              float* __restrict__ out, int M) {
    __shared__ ushort sA[128 * 64];
    __shared__ ushort sB[256 * 64];
    __shared__ ushort ht[128 * 256];

    int m0 = blockIdx.x * 128;
    int tid = threadIdx.x, wv = tid >> 6, lane = tid & 63;
    int lr = lane & 15;
    int kq = (lane >> 4) << 3;
    int l8 = (lane >> 3) & 7, c8 = lane & 7;
    int swz8 = c8 ^ l8;

    int wrow0 = (wv >> 2) * 64;   // stage1/2 wave grid: 2M x 4N, 64x64 per wave
    int wcol0 = (wv & 3) * 64;
    int crow = (lane >> 4) << 2;

    f32x4 acc[4][4];

    // ======== stage 1: h1 = relu(hsum @ W1 + b1), K=128 ========
#pragma unroll
    for (int m = 0; m < 4; ++m)
#pragma unroll
        for (int n = 0; n < 4; ++n) acc[m][n] = 0;

    for (int kb = 0; kb < 128; kb += 64) {
#pragma unroll
        for (int i = 0; i < 2; ++i) {
            int rg = i * 64 + wv * 8;
            gload16(hsum + (size_t)(m0 + rg + l8) * 128 + kb + swz8 * 8, sA + rg * 64);
        }
#pragma unroll
        for (int i = 0; i < 4; ++i) {
            int rg = i * 64 + wv * 8;
            gload16(W1T + (size_t)(rg + l8) * 128 + kb + swz8 * 8, sB + rg * 64);
        }
        __syncthreads();
#pragma unroll
        for (int kk = 0; kk < 64; kk += 32) {
            int cb = (kk + kq) * 2;
            bf16x8 af[4], bfr[4];
#pragma unroll
            for (int m = 0; m < 4; ++m) {
                int r = wrow0 + m * 16 + lr;
                af[m] = __builtin_bit_cast(bf16x8,
                    *(const uint4*)((const char*)sA + r * 128 + (cb ^ ((r & 7) << 4))));
            }
#pragma unroll
            for (int n = 0; n < 4; ++n) {
                int r = wcol0 + n * 16 + lr;
                bfr[n] = __builtin_bit_cast(bf16x8,
                    *(const uint4*)((const char*)sB + r * 128 + (cb ^ ((r & 7) << 4))));
            }
#pragma unroll
            for (int m = 0; m < 4; ++m)
#pragma unroll
                for (int n = 0; n < 4; ++n)
                    acc[m][n] = __builtin_amdgcn_mfma_f32_16x16x32_bf16(
                        af[m], bfr[n], acc[m][n], 0, 0, 0);
        }
        __syncthreads();
    }
#pragma unroll
    for (int n = 0; n < 4; ++n) {
        int col = wcol0 + n * 16 + lr;
        float bv = b1[col];
#pragma unroll
        for (int m = 0; m < 4; ++m) {
#pragma unroll
            for (int r = 0; r < 4; ++r) {
                int row = wrow0 + m * 16 + crow + r;
                int sc = ((((col >> 3) ^ (row & 7)) << 3) | (col & 7));
                ht[row * 256 + sc] = f2bf(fmaxf(acc[m][n][r] + bv, 0.0f));
            }
        }
    }
    __syncthreads();

    // ======== stage 2: h2 = relu(h1 @ W2 + b2), K=256 ========
#pragma unroll
    for (int m = 0; m < 4; ++m)
#pragma unroll
        for (int n = 0; n < 4; ++n) acc[m][n] = 0;

    for (int kb = 0; kb < 256; kb += 64) {
#pragma unroll
        for (int i = 0; i < 4; ++i) {
            int rg = i * 64 + wv * 8;
            gload16(W2T + (size_t)(rg + l8) * 256 + kb + swz8 * 8, sB + rg * 64);
        }
        __syncthreads();
#pragma unroll
        for (int kk = 0; kk < 64; kk += 32) {
            int cc = kb + kk + kq;
            int cb = (kk + kq) * 2;
            bf16x8 af[4], bfr[4];
#pragma unroll
            for (int m = 0; m < 4; ++m) {
                int r = wrow0 + m * 16 + lr;
                af[m] = __builtin_bit_cast(bf16x8,
                    *(const uint4*)(ht + r * 256 + ((((cc >> 3) ^ (r & 7)) << 3))));
            }
#pragma unroll
            for (int n = 0; n < 4; ++n) {
                int r = wcol0 + n * 16 + lr;
                bfr[n] = __builtin_bit_cast(bf16x8,
                    *(const uint4*)((const char*)sB + r * 128 + (cb ^ ((r & 7) << 4))));
            }
#pragma unroll
            for (int m = 0; m < 4; ++m)
#pragma unroll
                for (int n = 0; n < 4; ++n)
                    acc[m][n] = __builtin_amdgcn_mfma_f32_16x16x32_bf16(
                        af[m], bfr[n], acc[m][n], 0, 0, 0);
        }
        __syncthreads();
    }
    // epilogue 2: overwrite ht with relu(h2); also stage WcT into sB
#pragma unroll
    for (int n = 0; n < 4; ++n) {
        int col = wcol0 + n * 16 + lr;
        float bv = b2[col];
#pragma unroll
        for (int m = 0; m < 4; ++m) {
#pragma unroll
            for (int r = 0; r < 4; ++r) {
                int row = wrow0 + m * 16 + crow + r;
                int sc = ((((col >> 3) ^ (row & 7)) << 3) | (col & 7));
                ht[row * 256 + sc] = f2bf(fmaxf(acc[m][n][r] + bv, 0.0f));
            }
        }
    }
#pragma unroll
    for (int i = 0; i < 4; ++i)
        gload16(WcT + (size_t)(wv * 8 + l8) * 256 + i * 64 + swz8 * 8,
                sB + i * 4096 + wv * 8 * 64);
    __syncthreads();

    // ======== stage 3: out = h2 @ Wc + bc, K=256, N=64 ========
    f32x4 acc3[4];
#pragma unroll
    for (int n = 0; n < 4; ++n) acc3[n] = 0;
    int arow3 = wv * 16 + lr;   // 8 waves x 16 rows
#pragma unroll
    for (int kb4 = 0; kb4 < 4; ++kb4) {
#pragma unroll
        for (int kk = 0; kk < 64; kk += 32) {
            int cc = kb4 * 64 + kk + kq;
            int cb = (kk + kq) * 2;
            bf16x8 a = __builtin_bit_cast(bf16x8,
                *(const uint4*)(ht + arow3 * 256 + ((((cc >> 3) ^ (arow3 & 7)) << 3))));
#pragma unroll
            for (int n = 0; n < 4; ++n) {
                int r = n * 16 + lr;
                bf16x8 b = __builtin_bit_cast(bf16x8,
                    *(const uint4*)((const char*)sB + kb4 * 8192 + r * 128 +
                                    (cb ^ ((r & 7) << 4))));
                acc3[n] = __builtin_amdgcn_mfma_f32_16x16x32_bf16(a, b, acc3[n], 0, 0, 0);
            }
        }
    }
#pragma unroll
    for (int n = 0; n < 4; ++n) {
        int col = n * 16 + lr;
        float bv = bc[col];
#pragma unroll
        for (int r = 0; r < 4; ++r) {
            int grow = m0 + wv * 16 + crow + r;
            if (grow < M) out[(size_t)grow * 64 + col] = acc3[n][r] + bv;
        }
    }
}

// ---------------- launch ----------------

extern "C" void kernel_launch(void* const* d_in, const int* in_sizes, int n_in,
                              void* d_out, int out_size, void* d_ws, size_t ws_size,
                              hipStream_t stream) {
    const float* x  = (const float*)d_in[0];
    const int*   ei = (const int*)d_in[1];   // [2, 800000]: row0 = src, row1 = dst
    const float* W1 = (const float*)d_in[2];
    const float* b1 = (const float*)d_in[3];
    const float* W2 = (const float*)d_in[4];
    const float* b2 = (const float*)d_in[5];
    const float* Wc = (const float*)d_in[6];
    const float* bc = (const float*)d_in[7];
    float* out = (float*)d_out;

    char* p = (char*)d_ws;
    int* bcnt   = (int*)p; p += 400 * 4;
    int* bcur0  = (int*)p; p += 400 * 4;
    uint2* pbuf = (uint2*)p; p += (size_t)N_EDGES * 8;
    ushort* W1T = (ushort*)p; p += 256 * 128 * 2;
    ushort* W2T = (ushort*)p; p += 256 * 256 * 2;
    ushort* WcT = (ushort*)p; p += 64 * 256 * 2;
    ushort* xb  = (ushort*)p; p += (size_t)N_NODES * 128 * 2;
    ushort* hsum = (ushort*)p; p += (size_t)M_PAD * 128 * 2;

    k_prep<<<NB_CAST + NB_TR + 1, 256, 0, stream>>>(x, xb, W1, W1T, W2, W2T, Wc, WcT,
                                                    bcnt, bcur0);
    k_bhist<<<NB_EB, 256, 0, stream>>>(ei, bcnt);
    k_bscatter<<<NB_EB, 512, 0, stream>>>(ei, bcnt, bcur0, pbuf);
    k_agg2<<<NBUCK, 256, 0, stream>>>(pbuf, bcnt, xb, hsum);
    k_mlp3<<<M_PAD / 128, 512, 0, stream>>>(hsum, W1T, b1, W2T, b2, WcT, bc, out, N_NODES);
}

// Round 9
// 101.027 us; speedup vs baseline: 2.5755x; 1.2119x over previous
//
#include <hip/hip_runtime.h>
#include <hip/hip_bf16.h>

#define N_NODES 50000
#define M_PAD   50048   // 391 * 128
#define N_EDGES 800000
#define NBUCK   391     // bucket = dst>>7 -> 128 nodes per bucket
#define NB_EB   391     // ceil(800000/2048)
#define NB_CAST 3125    // 50000*128/8/256
#define NB_TR   448     // (128*256+256*256+256*64)/256
#define EBMAX   4096    // fixed per-bucket capacity (actual max ~2270)

typedef __bf16 bf16x8 __attribute__((ext_vector_type(8)));
typedef float  f32x4  __attribute__((ext_vector_type(4)));

__device__ __forceinline__ ushort f2bf(float f) {
    __hip_bfloat16 h = __float2bfloat16(f);
    return __builtin_bit_cast(ushort, h);
}
__device__ __forceinline__ float bf2f(ushort u) {
    return __builtin_bit_cast(float, (unsigned)u << 16);
}

// async global->LDS, 16B per lane; lds base must be wave-uniform
__device__ __forceinline__ void gload16(const ushort* g, ushort* l) {
    __builtin_amdgcn_global_load_lds(
        (const __attribute__((address_space(1))) unsigned*)g,
        (__attribute__((address_space(3))) unsigned*)l, 16, 0, 0);
}

// ---------------- prep: x cast + weight transpose + cursor zeroing ----------------
__device__ __forceinline__ void transpose_one(const float* W, ushort* WT,
                                              int K, int N, int t) {
    int k = t / N, n = t % N;
    WT[n * K + k] = f2bf(W[t]);
}

__global__ __launch_bounds__(256) void k_prep(const float* __restrict__ x,
                                              ushort* __restrict__ xb,
                                              const float* __restrict__ W1, ushort* __restrict__ W1T,
                                              const float* __restrict__ W2, ushort* __restrict__ W2T,
                                              const float* __restrict__ Wc, ushort* __restrict__ WcT,
                                              int* __restrict__ bcur) {
    int b = blockIdx.x, t = threadIdx.x;
    if (b < NB_CAST) {
        int i = b * 256 + t;  // 8 elems each
        const float4* x4 = (const float4*)x;
        float4 a = x4[(size_t)i * 2], bb = x4[(size_t)i * 2 + 1];
        ushort o[8];
        o[0] = f2bf(a.x); o[1] = f2bf(a.y); o[2] = f2bf(a.z); o[3] = f2bf(a.w);
        o[4] = f2bf(bb.x); o[5] = f2bf(bb.y); o[6] = f2bf(bb.z); o[7] = f2bf(bb.w);
        *(uint4*)(xb + (size_t)i * 8) = *(uint4*)o;
    } else if (b < NB_CAST + NB_TR) {
        int tg = (b - NB_CAST) * 256 + t;
        const int S1 = 128 * 256, S2 = 256 * 256, S3 = 256 * 64;
        if (tg < S1) transpose_one(W1, W1T, 128, 256, tg);
        else if (tg < S1 + S2) transpose_one(W2, W2T, 256, 256, tg - S1);
        else if (tg < S1 + S2 + S3) transpose_one(Wc, WcT, 256, 64, tg - S1 - S2);
    } else {
        for (int i = t; i < 400; i += 256) bcur[i] = 0;
    }
}

// ---------------- bucket scatter: fixed-capacity regions, no histogram pass ----------------
// pbuf[bk*EBMAX + pos] = src | ((dst&127)<<17). Final bcur[bk] = bucket count.
__global__ __launch_bounds__(512) void k_bscatter(const int* __restrict__ ei,
                                                  int* __restrict__ bcur,
                                                  unsigned* __restrict__ pbuf) {
    __shared__ int lh[NBUCK];
    __shared__ int lbase[NBUCK];
    int t = threadIdx.x;
    for (int i = t; i < NBUCK; i += 512) lh[i] = 0;
    __syncthreads();
    int base = blockIdx.x * 2048 + t;
    int s[4], bk[4], rk[4], lo[4];
#pragma unroll
    for (int k = 0; k < 4; ++k) {
        int e = base + k * 512;
        bool ok = e < N_EDGES;
        int ee = ok ? e : 0;
        s[k] = ei[ee];
        int d = ei[N_EDGES + ee];
        bk[k] = ok ? (d >> 7) : -1;
        lo[k] = d & 127;
    }
#pragma unroll
    for (int k = 0; k < 4; ++k)
        if (bk[k] >= 0) rk[k] = atomicAdd(&lh[bk[k]], 1);
    __syncthreads();
    for (int i = t; i < NBUCK; i += 512) {
        int v = lh[i];
        lbase[i] = v ? atomicAdd(&bcur[i], v) : 0;
    }
    __syncthreads();
#pragma unroll
    for (int k = 0; k < 4; ++k)
        if (bk[k] >= 0) {
            int pos = lbase[bk[k]] + rk[k];
            if (pos < EBMAX)
                pbuf[bk[k] * EBMAX + pos] = (unsigned)s[k] | ((unsigned)lo[k] << 17);
        }
}

// ---------------- bucket place: per-node LDS count/scan -> nodestart/nodecnt + elist ----------------
__global__ __launch_bounds__(256) void k_bplace(const unsigned* __restrict__ pbuf,
                                                const int* __restrict__ bcur,
                                                int* __restrict__ nodestart,
                                                int* __restrict__ nodecnt,
                                                int* __restrict__ elist) {
    __shared__ int lcnt[128], lexc[128], lcur[128];
    int b = blockIdx.x, t = threadIdx.x;
    int m = bcur[b]; if (m > EBMAX) m = EBMAX;
    const unsigned* pb = pbuf + b * EBMAX;
    if (t < 128) lcnt[t] = 0;
    __syncthreads();
    for (int i = t; i < m; i += 256)
        atomicAdd(&lcnt[pb[i] >> 17], 1);
    __syncthreads();
    if (t < 128) lexc[t] = lcnt[t];
    __syncthreads();
#pragma unroll
    for (int off = 1; off < 128; off <<= 1) {
        int u = (t < 128 && t >= off) ? lexc[t - off] : 0;
        __syncthreads();
        if (t < 128) lexc[t] += u;
        __syncthreads();
    }
    if (t < 128) {
        int e = lexc[t] - lcnt[t];
        int node = (b << 7) + t;
        if (node < N_NODES) {
            nodestart[node] = b * EBMAX + e;
            nodecnt[node] = lcnt[t];
        }
        lcur[t] = e;
    }
    __syncthreads();
    for (int i = t; i < m; i += 256) {
        unsigned pr = pb[i];
        int pos = atomicAdd(&lcur[pr >> 17], 1);
        elist[b * EBMAX + pos] = (int)(pr & 0x1FFFF);
    }
}

// ---------------- aggregation: wide grid + batch-8 gather ILP ----------------
__global__ __launch_bounds__(256) void k_aggregate(const ushort* __restrict__ xb,
                                                   const int* __restrict__ nodestart,
                                                   const int* __restrict__ nodecnt,
                                                   const int* __restrict__ elist,
                                                   ushort* __restrict__ hsum) {
    int g = threadIdx.x >> 5, lane = threadIdx.x & 31;
    int node = blockIdx.x * 8 + g;
    if (node >= N_NODES) return;
    const ushort4* x4 = (const ushort4*)xb;
    ushort4 mine = x4[(size_t)node * 32 + lane];
    float acc0 = bf2f(mine.x), acc1 = bf2f(mine.y), acc2 = bf2f(mine.z), acc3 = bf2f(mine.w);
    int beg = nodestart[node], cnt = nodecnt[node];
    for (int base = 0; base < cnt; base += 32) {
        int mrem = cnt - base;
        int idx = (lane < mrem) ? elist[beg + base + lane] : 0;
        int c = mrem < 32 ? mrem : 32;
        int j = 0;
        for (; j + 8 <= c; j += 8) {
            ushort4 v[8];
#pragma unroll
            for (int u = 0; u < 8; ++u) {
                int s = __shfl(idx, j + u, 32);
                v[u] = x4[(size_t)s * 32 + lane];
            }
#pragma unroll
            for (int u = 0; u < 8; ++u) {
                acc0 += bf2f(v[u].x); acc1 += bf2f(v[u].y);
                acc2 += bf2f(v[u].z); acc3 += bf2f(v[u].w);
            }
        }
        for (; j < c; ++j) {
            int s = __shfl(idx, j, 32);
            ushort4 v = x4[(size_t)s * 32 + lane];
            acc0 += bf2f(v.x); acc1 += bf2f(v.y); acc2 += bf2f(v.z); acc3 += bf2f(v.w);
        }
    }
    ushort4 o;
    o.x = f2bf(acc0); o.y = f2bf(acc1); o.z = f2bf(acc2); o.w = f2bf(acc3);
    *(ushort4*)(hsum + (size_t)node * 128 + lane * 4) = o;
}

// ---------------- fully-fused 3-stage MLP (unchanged) ----------------
__global__ __launch_bounds__(512) void k_mlp3(const ushort* __restrict__ hsum,
                                              const ushort* __restrict__ W1T,
                                              const float* __restrict__ b1,
                                              const ushort* __restrict__ W2T,
                                              const float* __restrict__ b2,
                                              const ushort* __restrict__ WcT,
                                              const float* __restrict__ bc,
                                              float* __restrict__ out, int M) {
    __shared__ ushort sA[128 * 64];
    __shared__ ushort sB[256 * 64];
    __shared__ ushort ht[128 * 256];

    int m0 = blockIdx.x * 128;
    int tid = threadIdx.x, wv = tid >> 6, lane = tid & 63;
    int lr = lane & 15;
    int kq = (lane >> 4) << 3;
    int l8 = (lane >> 3) & 7, c8 = lane & 7;
    int swz8 = c8 ^ l8;

    int wrow0 = (wv >> 2) * 64;   // stage1/2 wave grid: 2M x 4N, 64x64 per wave
    int wcol0 = (wv & 3) * 64;
    int crow = (lane >> 4) << 2;

    f32x4 acc[4][4];

    // ======== stage 1: h1 = relu(hsum @ W1 + b1), K=128 ========
#pragma unroll
    for (int m = 0; m < 4; ++m)
#pragma unroll
        for (int n = 0; n < 4; ++n) acc[m][n] = 0;

    for (int kb = 0; kb < 128; kb += 64) {
#pragma unroll
        for (int i = 0; i < 2; ++i) {
            int rg = i * 64 + wv * 8;
            gload16(hsum + (size_t)(m0 + rg + l8) * 128 + kb + swz8 * 8, sA + rg * 64);
        }
#pragma unroll
        for (int i = 0; i < 4; ++i) {
            int rg = i * 64 + wv * 8;
            gload16(W1T + (size_t)(rg + l8) * 128 + kb + swz8 * 8, sB + rg * 64);
        }
        __syncthreads();
#pragma unroll
        for (int kk = 0; kk < 64; kk += 32) {
            int cb = (kk + kq) * 2;
            bf16x8 af[4], bfr[4];
#pragma unroll
            for (int m = 0; m < 4; ++m) {
                int r = wrow0 + m * 16 + lr;
                af[m] = __builtin_bit_cast(bf16x8,
                    *(const uint4*)((const char*)sA + r * 128 + (cb ^ ((r & 7) << 4))));
            }
#pragma unroll
            for (int n = 0; n < 4; ++n) {
                int r = wcol0 + n * 16 + lr;
                bfr[n] = __builtin_bit_cast(bf16x8,
                    *(const uint4*)((const char*)sB + r * 128 + (cb ^ ((r & 7) << 4))));
            }
#pragma unroll
            for (int m = 0; m < 4; ++m)
#pragma unroll
                for (int n = 0; n < 4; ++n)
                    acc[m][n] = __builtin_amdgcn_mfma_f32_16x16x32_bf16(
                        af[m], bfr[n], acc[m][n], 0, 0, 0);
        }
        __syncthreads();
    }
#pragma unroll
    for (int n = 0; n < 4; ++n) {
        int col = wcol0 + n * 16 + lr;
        float bv = b1[col];
#pragma unroll
        for (int m = 0; m < 4; ++m) {
#pragma unroll
            for (int r = 0; r < 4; ++r) {
                int row = wrow0 + m * 16 + crow + r;
                int sc = ((((col >> 3) ^ (row & 7)) << 3) | (col & 7));
                ht[row * 256 + sc] = f2bf(fmaxf(acc[m][n][r] + bv, 0.0f));
            }
        }
    }
    __syncthreads();

    // ======== stage 2: h2 = relu(h1 @ W2 + b2), K=256 ========
#pragma unroll
    for (int m = 0; m < 4; ++m)
#pragma unroll
        for (int n = 0; n < 4; ++n) acc[m][n] = 0;

    for (int kb = 0; kb < 256; kb += 64) {
#pragma unroll
        for (int i = 0; i < 4; ++i) {
            int rg = i * 64 + wv * 8;
            gload16(W2T + (size_t)(rg + l8) * 256 + kb + swz8 * 8, sB + rg * 64);
        }
        __syncthreads();
#pragma unroll
        for (int kk = 0; kk < 64; kk += 32) {
            int cc = kb + kk + kq;
            int cb = (kk + kq) * 2;
            bf16x8 af[4], bfr[4];
#pragma unroll
            for (int m = 0; m < 4; ++m) {
                int r = wrow0 + m * 16 + lr;
                af[m] = __builtin_bit_cast(bf16x8,
                    *(const uint4*)(ht + r * 256 + ((((cc >> 3) ^ (r & 7)) << 3))));
            }
#pragma unroll
            for (int n = 0; n < 4; ++n) {
                int r = wcol0 + n * 16 + lr;
                bfr[n] = __builtin_bit_cast(bf16x8,
                    *(const uint4*)((const char*)sB + r * 128 + (cb ^ ((r & 7) << 4))));
            }
#pragma unroll
            for (int m = 0; m < 4; ++m)
#pragma unroll
                for (int n = 0; n < 4; ++n)
                    acc[m][n] = __builtin_amdgcn_mfma_f32_16x16x32_bf16(
                        af[m], bfr[n], acc[m][n], 0, 0, 0);
        }
        __syncthreads();
    }
    // epilogue 2: overwrite ht with relu(h2); also stage WcT into sB
#pragma unroll
    for (int n = 0; n < 4; ++n) {
        int col = wcol0 + n * 16 + lr;
        float bv = b2[col];
#pragma unroll
        for (int m = 0; m < 4; ++m) {
#pragma unroll
            for (int r = 0; r < 4; ++r) {
                int row = wrow0 + m * 16 + crow + r;
                int sc = ((((col >> 3) ^ (row & 7)) << 3) | (col & 7));
                ht[row * 256 + sc] = f2bf(fmaxf(acc[m][n][r] + bv, 0.0f));
            }
        }
    }
#pragma unroll
    for (int i = 0; i < 4; ++i)
        gload16(WcT + (size_t)(wv * 8 + l8) * 256 + i * 64 + swz8 * 8,
                sB + i * 4096 + wv * 8 * 64);
    __syncthreads();

    // ======== stage 3: out = h2 @ Wc + bc, K=256, N=64 ========
    f32x4 acc3[4];
#pragma unroll
    for (int n = 0; n < 4; ++n) acc3[n] = 0;
    int arow3 = wv * 16 + lr;   // 8 waves x 16 rows
#pragma unroll
    for (int kb4 = 0; kb4 < 4; ++kb4) {
#pragma unroll
        for (int kk = 0; kk < 64; kk += 32) {
            int cc = kb4 * 64 + kk + kq;
            int cb = (kk + kq) * 2;
            bf16x8 a = __builtin_bit_cast(bf16x8,
                *(const uint4*)(ht + arow3 * 256 + ((((cc >> 3) ^ (arow3 & 7)) << 3))));
#pragma unroll
            for (int n = 0; n < 4; ++n) {
                int r = n * 16 + lr;
                bf16x8 b = __builtin_bit_cast(bf16x8,
                    *(const uint4*)((const char*)sB + kb4 * 8192 + r * 128 +
                                    (cb ^ ((r & 7) << 4))));
                acc3[n] = __builtin_amdgcn_mfma_f32_16x16x32_bf16(a, b, acc3[n], 0, 0, 0);
            }
        }
    }
#pragma unroll
    for (int n = 0; n < 4; ++n) {
        int col = n * 16 + lr;
        float bv = bc[col];
#pragma unroll
        for (int r = 0; r < 4; ++r) {
            int grow = m0 + wv * 16 + crow + r;
            if (grow < M) out[(size_t)grow * 64 + col] = acc3[n][r] + bv;
        }
    }
}

// ---------------- launch ----------------

extern "C" void kernel_launch(void* const* d_in, const int* in_sizes, int n_in,
                              void* d_out, int out_size, void* d_ws, size_t ws_size,
                              hipStream_t stream) {
    const float* x  = (const float*)d_in[0];
    const int*   ei = (const int*)d_in[1];   // [2, 800000]: row0 = src, row1 = dst
    const float* W1 = (const float*)d_in[2];
    const float* b1 = (const float*)d_in[3];
    const float* W2 = (const float*)d_in[4];
    const float* b2 = (const float*)d_in[5];
    const float* Wc = (const float*)d_in[6];
    const float* bc = (const float*)d_in[7];
    float* out = (float*)d_out;

    char* p = (char*)d_ws;
    int* bcur        = (int*)p; p += 400 * 4;
    int* nodestart   = (int*)p; p += M_PAD * 4;
    int* nodecnt     = (int*)p; p += M_PAD * 4;
    unsigned* pbuf   = (unsigned*)p; p += (size_t)NBUCK * EBMAX * 4;
    int* elist       = (int*)p; p += (size_t)NBUCK * EBMAX * 4;
    ushort* W1T = (ushort*)p; p += 256 * 128 * 2;
    ushort* W2T = (ushort*)p; p += 256 * 256 * 2;
    ushort* WcT = (ushort*)p; p += 64 * 256 * 2;
    ushort* xb  = (ushort*)p; p += (size_t)N_NODES * 128 * 2;
    ushort* hsum = (ushort*)p; p += (size_t)M_PAD * 128 * 2;

    k_prep<<<NB_CAST + NB_TR + 1, 256, 0, stream>>>(x, xb, W1, W1T, W2, W2T, Wc, WcT, bcur);
    k_bscatter<<<NB_EB, 512, 0, stream>>>(ei, bcur, pbuf);
    k_bplace<<<NBUCK, 256, 0, stream>>>(pbuf, bcur, nodestart, nodecnt, elist);
    k_aggregate<<<(N_NODES + 7) / 8, 256, 0, stream>>>(xb, nodestart, nodecnt, elist, hsum);
    k_mlp3<<<M_PAD / 128, 512, 0, stream>>>(hsum, W1T, b1, W2T, b2, WcT, bc, out, N_NODES);
}